// Round 1
// baseline (308.325 us; speedup 1.0000x reference)
//
#include <hip/hip_runtime.h>
#include <hip/hip_cooperative_groups.h>
#include <stdint.h>

namespace cg = cooperative_groups;

// ===========================================================================
// AnchorDataGenerator (Faster R-CNN anchor target layer), MI355X / gfx950
// Round 4: single fused cooperative kernel (4 dispatches -> 1).
//  - Phase A: per-gt windowed gmax, 9 slices/gt (576 blocks exact); also
//    zeroes the ws control region.                       grid.sync()
//  - Phase B: verbatim k_main compute (labels/adj/mantissa/hist); per-anchor
//    (label,mantissa) kept IN REGISTERS (LABM buffer eliminated); done-counter
//    last block computes subsample boundaries.           grid.sync()
//  - Phase C: emit labels/wts from registers + boundary candidate push.
//                                                        grid.sync()
//  - Phase D: blocks 0/1 rank boundary candidates in LDS, promote rank<need.
// Cross-phase scalars read via __hip_atomic_load (AGENT). IoU math bit-exact
// vs reference (contract off, IEEE div, same op order).
// Fallback: proven 4-kernel path if cooperative launch is rejected.
// ===========================================================================

#define NUM_A 9
#define HW 65536
#define N_ANCH 589824
#define NG 64
#define CAPK 128u
#define NBIN 2048
#define BIN_SHIFT 12
#define CAND_CAP 4096

#define LAB_BG 0u
#define LAB_FG 1u
#define LAB_IGN 2u

// ---- fused-kernel workspace layout (u32 units), ~86 KB used ----
#define F_OFF_GMAX 0                         // 64 gts x 16 (9 slices used)
#define F_OFF_HF   1024
#define F_OFF_HB   (F_OFF_HF + NBIN)         // 3072
#define F_OFF_CNTF (F_OFF_HF + 2*NBIN)       // 5120
#define F_OFF_CNTB (F_OFF_CNTF + 1)          // 5121
#define F_OFF_DONE (F_OFF_CNTF + 2)          // 5122
#define F_OFF_SEL  (F_OFF_CNTF + 4)          // 5124..5131: {bin,below,need,K}x2
#define F_OFF_CANDF 5132                     // even word -> 8B aligned
#define F_OFF_CANDB (F_OFF_CANDF + 2*CAND_CAP) // 13324
#define F_ZERO_BEG F_OFF_HF
#define F_NZ (F_OFF_CANDF - F_OFF_HF)        // 4108 words

// ---- legacy 4-kernel layout (fallback path only) ----
#define OFF_GMAX8 0
#define OFF_HF    512
#define OFF_HB    (OFF_HF + NBIN)
#define OFF_CNTF  (OFF_HF + 2*NBIN)
#define OFF_CNTB  (OFF_CNTF + 1)
#define OFF_DONE2 (OFF_CNTF + 2)
#define OFF_SEL   (OFF_CNTF + 4)
#define OFF_CANDF 4620
#define OFF_CANDB (OFF_CANDF + 2*CAND_CAP)
#define OFF_LABM  (OFF_CANDB + 2*CAND_CAP)
#define ZERO_BEG  OFF_HF
#define ZERO_END  OFF_CANDF
#define NZ        (ZERO_END - ZERO_BEG)

__constant__ float BA[NUM_A][4] = {
  { -84.f,  -40.f,  99.f,  55.f}, {-176.f,  -88.f, 191.f, 103.f},
  {-360.f, -184.f, 375.f, 199.f}, { -56.f,  -56.f,  71.f,  71.f},
  {-120.f, -120.f, 135.f, 135.f}, {-248.f, -248.f, 263.f, 263.f},
  { -36.f,  -80.f,  51.f,  95.f}, { -80.f, -168.f,  95.f, 183.f},
  {-168.f, -344.f, 183.f, 359.f}};

__host__ __device__ static inline void tf2x32(uint32_t k0, uint32_t k1,
                                              uint32_t x0, uint32_t x1,
                                              uint32_t* o0, uint32_t* o1) {
  const uint32_t ks2 = k0 ^ k1 ^ 0x1BD11BDAu;
#define TF_R(r) { x0 += x1; x1 = (x1 << (r)) | (x1 >> (32 - (r))); x1 ^= x0; }
  x0 += k0; x1 += k1;
  TF_R(13) TF_R(15) TF_R(26) TF_R(6)
  x0 += k1;  x1 += ks2 + 1u;
  TF_R(17) TF_R(29) TF_R(16) TF_R(24)
  x0 += ks2; x1 += k0 + 2u;
  TF_R(13) TF_R(15) TF_R(26) TF_R(6)
  x0 += k0;  x1 += k1 + 3u;
  TF_R(17) TF_R(29) TF_R(16) TF_R(24)
  x0 += k1;  x1 += ks2 + 4u;
  TF_R(13) TF_R(15) TF_R(26) TF_R(6)
  x0 += ks2; x1 += k0 + 5u;
#undef TF_R
  *o0 = x0; *o1 = x1;
}

__device__ static inline uint32_t mant_of(uint32_t k0, uint32_t k1, uint32_t n) {
  uint32_t o0, o1;
  tf2x32(k0, k1, 0u, n, &o0, &o1);
  return (o0 ^ o1) >> 9;
}

__device__ static inline float iou1(float a0, float a1, float a2, float a3,
                                    float aarea, float g0, float g1, float g2,
                                    float g3, float garea) {
  #pragma clang fp contract(off)
  float ix1 = fmaxf(a0, g0);
  float iy1 = fmaxf(a1, g1);
  float ix2 = fminf(a2, g2);
  float iy2 = fminf(a3, g3);
  float iw = ix2 - ix1 + 1.0f;
  float ih = iy2 - iy1 + 1.0f;
  float inter = (iw > 0.0f && ih > 0.0f) ? iw * ih : 0.0f;
  float den = aarea + garea - inter;
  return inter / den;
}

// ===========================================================================
// Fused cooperative kernel
// ===========================================================================
__global__ __launch_bounds__(256, 3) void k_fused(
    const float* __restrict__ gt, const int* __restrict__ imw_p,
    const int* __restrict__ imh_p, float* __restrict__ out_lab,
    float* __restrict__ out_adj, float* __restrict__ out_wts,
    uint32_t* __restrict__ ws, uint32_t kf0, uint32_t kf1, uint32_t kb0,
    uint32_t kb1) {
  #pragma clang fp contract(off)
  cg::grid_group grd = cg::this_grid();

  // 32 KB shared, aliased per phase.
  __shared__ uint64_t SMEM[CAND_CAP];
  uint32_t* SW = (uint32_t*)SMEM;
  float* sg0 = (float*)(SW + 0);            // [64]
  float* sg1 = (float*)(SW + 64);
  float* sg2 = (float*)(SW + 128);
  float* sg3 = (float*)(SW + 192);
  float* sga = (float*)(SW + 256);
  float* sgm = (float*)(SW + 320);
  uint32_t* sh = SW + 384;                  // [4096], 16B aligned
  unsigned long long* sMask = (unsigned long long*)(SW + 4480); // [4]
  int* sAnyZero = (int*)(SW + 4488);
  int* sLast = (int*)(SW + 4489);
  float* wmax = (float*)(SW + 4490);        // [4]

  int tid = threadIdx.x;
  int b = blockIdx.x;

  // ---- Phase A: zero ws ctrl region + windowed per-gt gmax (9 slices/gt)
  {
    int gid = b * 256 + tid;
    if (gid < F_NZ) ws[F_ZERO_BEG + gid] = 0u;

    int g = b / 9, sl = b - g * 9;
    float g0 = gt[g*4+0], g1 = gt[g*4+1], g2 = gt[g*4+2], g3 = gt[g*4+3];
    float gw = g2 - g0 + 1.0f, gh = g3 - g1 + 1.0f;
    float ga = (gw > 0.0f && gh > 0.0f) ? gw * gh : 0.0f;
    float imw = (float)imw_p[0], imh = (float)imh_p[0];

    float mx = 0.0f;
    for (int aa = 0; aa < NUM_A; aa++) {
      float b0 = BA[aa][0], b1 = BA[aa][1], b2 = BA[aa][2], b3 = BA[aa][3];
      int wlo = max(0,   (int)floorf((g0 - 1.0f - b2) * 0.0625f));
      int whi = min(255, (int)ceilf ((g2 + 1.0f - b0) * 0.0625f));
      int hlo = max(0,   (int)floorf((g1 - 1.0f - b3) * 0.0625f));
      int hhi = min(255, (int)ceilf ((g3 + 1.0f - b1) * 0.0625f));
      int wx = whi - wlo + 1, wy = hhi - hlo + 1;
      if (wx <= 0 || wy <= 0) continue;
      int tot = wx * wy;
      for (int idx = sl * 256 + tid; idx < tot; idx += 2304) {
        int h = hlo + idx / wx, w2 = wlo + idx % wx;
        float sx = (float)(w2 << 4), sy = (float)(h << 4);
        float x1 = b0 + sx, y1 = b1 + sy, x2 = b2 + sx, y2 = b3 + sy;
        float aw = x2 - x1 + 1.0f, ah = y2 - y1 + 1.0f;
        float aarea = aw * ah;
        bool vld = (x1 >= 0.0f) && (y1 >= 0.0f) && (x2 < imw) && (y2 < imh);
        float o = iou1(x1, y1, x2, y2, aarea, g0, g1, g2, g3, ga);
        if (vld) mx = fmaxf(mx, o);
      }
    }
    #pragma unroll
    for (int s = 32; s >= 1; s >>= 1) mx = fmaxf(mx, __shfl_xor(mx, s, 64));
    if ((tid & 63) == 0) wmax[tid >> 6] = mx;
    __syncthreads();
    if (tid == 0) {
      float m = fmaxf(fmaxf(wmax[0], wmax[1]), fmaxf(wmax[2], wmax[3]));
      ws[F_OFF_GMAX + g * 16 + sl] = __float_as_uint(m);
    }
  }

  grd.sync();

  // ---- Phase B: main compute (verbatim k_main, LABM -> registers) ----
  {
    uint4* sh4 = (uint4*)sh;
    #pragma unroll
    for (int k = 0; k < 4; k++) sh4[tid + k * 256] = make_uint4(0, 0, 0, 0);
  }
  if (tid == 0) *sAnyZero = 0;
  if (tid < NG) {
    const float4 g4 = ((const float4*)gt)[tid];
    sg0[tid] = g4.x; sg1[tid] = g4.y; sg2[tid] = g4.z; sg3[tid] = g4.w;
    float gw = g4.z - g4.x + 1.0f, gh = g4.w - g4.y + 1.0f;
    sga[tid] = (gw > 0.0f && gh > 0.0f) ? gw * gh : 0.0f;
    uint32_t mm = 0u;
    #pragma unroll
    for (int j = 0; j < 9; j++)
      mm = max(mm, __hip_atomic_load(&ws[F_OFF_GMAX + tid * 16 + j],
                                     __ATOMIC_RELAXED,
                                     __HIP_MEMORY_SCOPE_AGENT));
    sgm[tid] = __uint_as_float(mm);
    if (mm == 0u) atomicOr(sAnyZero, 1);
  }
  __syncthreads();

  int a = b >> 6, hb = (b & 63) << 2;      // anchor type, 4 rows hb..hb+3
  float BA0 = BA[a][0], BA1 = BA[a][1], BA2 = BA[a][2], BA3 = BA[a][3];

  {
    int wv = tid >> 6, g = tid & 63;
    float sy = (float)((hb + wv) << 4);
    float ihp = fminf(BA3 + sy, sg3[g]) - fmaxf(BA1 + sy, sg1[g]) + 1.0f;
    unsigned long long mk = __ballot(ihp > 0.0f);
    if (g == 0) sMask[wv] = mk;
  }
  __syncthreads();

  float imw = (float)imw_p[0], imh = (float)imh_p[0];
  int w = tid;
  float sx = (float)(w << 4);
  float A0 = BA0 + sx, A2 = BA2 + sx;
  float aw = A2 - A0 + 1.0f;
  float A1v[4], A3v[4];
  #pragma unroll
  for (int r = 0; r < 4; r++) {
    float sy = (float)((hb + r) << 4);
    A1v[r] = BA1 + sy; A3v[r] = BA3 + sy;
  }
  float ah = A3v[0] - A1v[0] + 1.0f;
  float aarea = aw * ah;
  bool xv = (A0 >= 0.0f) && (A2 < imw);

  unsigned long long mk0 = sMask[0], mk1 = sMask[1],
                     mk2 = sMask[2], mk3 = sMask[3];
  unsigned long long uni = mk0 | mk1 | mk2 | mk3;
  float amaxv[4] = {0.f, 0.f, 0.f, 0.f};
  int bgv[4] = {0, 0, 0, 0};
  uint32_t afv = 0u;
  while (uni) {
    int g = __ffsll(uni) - 1;
    uni &= uni - 1;
    float iw = fminf(A2, sg2[g]) - fmaxf(A0, sg0[g]) + 1.0f;
    if (!__any(iw > 0.0f)) continue;
    if (iw > 0.0f) {
      float base = aarea + sga[g];
      float gy1 = sg1[g], gy2 = sg3[g], gm = sgm[g];
#define DO_ROW(r, mk)                                                     \
      if ((mk >> g) & 1ull) {                                             \
        float ih = fminf(A3v[r], gy2) - fmaxf(A1v[r], gy1) + 1.0f;        \
        float inter = iw * ih;                                            \
        float o = inter / (base - inter);                                 \
        if (o > amaxv[r]) { amaxv[r] = o; bgv[r] = g; }                   \
        if (o == gm) afv |= (1u << r);                                    \
      }
      DO_ROW(0, mk0) DO_ROW(1, mk1) DO_ROW(2, mk2) DO_ROW(3, mk3)
#undef DO_ROW
    }
  }

  bool anyZ = (*sAnyZero != 0);
  uint32_t lm[4];
  #pragma unroll
  for (int r = 0; r < 4; r++) {
    int hw = (hb + r) * 256 + w;
    bool valid = xv && (A1v[r] >= 0.0f) && (A3v[r] < imh);
    float amax = amaxv[r];
    bool anyfg = (((afv >> r) & 1u) || anyZ) && valid;
    uint32_t lab;
    if (!valid)                       lab = LAB_IGN;
    else if (anyfg || amax >= 0.7f)   lab = LAB_FG;
    else if (amax < 0.3f)             lab = LAB_BG;
    else                              lab = LAB_IGN;

    float adj0 = 0.f, adj1 = 0.f, adj2 = 0.f, adj3 = 0.f;
    if (valid) {
      int bg = bgv[r];
      float G0 = sg0[bg], G1 = sg1[bg], G2 = sg2[bg], G3 = sg3[bg];
      float ax = (A2 + A0) * 0.5f, ay = (A3v[r] + A1v[r]) * 0.5f;
      float gwm = G2 - G0 + 1.0f, ghm = G3 - G1 + 1.0f;
      float gx = (G2 + G0) * 0.5f, gy = (G3 + G1) * 0.5f;
      adj0 = (gx - ax) / aw;
      adj1 = (gy - ay) / ah;
      adj2 = logf(gwm / aw);
      adj3 = logf(ghm / ah);
    }
    int c4 = a * 4;
    out_adj[(c4 + 0) * HW + hw] = adj0;
    out_adj[(c4 + 1) * HW + hw] = adj1;
    out_adj[(c4 + 2) * HW + hw] = adj2;
    out_adj[(c4 + 3) * HW + hw] = adj3;

    uint32_t m = 0u;
    uint32_t n = (uint32_t)(hw * 9 + a);
    if (lab != LAB_IGN) {
      uint32_t kk0 = (lab == LAB_FG) ? kf0 : kb0;
      uint32_t kk1 = (lab == LAB_FG) ? kf1 : kb1;
      m = mant_of(kk0, kk1, n);
      atomicAdd(&sh[((lab == LAB_FG) ? 0 : NBIN) + (m >> BIN_SHIFT)], 1u);
    }
    lm[r] = (lab << 24) | m;
  }

  __syncthreads();
  for (int i = tid; i < 2 * NBIN; i += 256) {
    uint32_t v = sh[i];
    if (v) atomicAdd(&ws[F_OFF_HF + i], v);
  }
  __syncthreads();
  if (tid == 0)
    *sLast = (atomicAdd(&ws[F_OFF_DONE], 1u) == 575u) ? 1 : 0;
  __syncthreads();
  if (*sLast) {
    for (int cls = 0; cls < 2; cls++) {
      uint32_t* hist = ws + (cls ? F_OFF_HB : F_OFF_HF);
      uint32_t* sel = ws + F_OFF_SEL + cls * 4;
      uint32_t loc[8], s = 0;
      #pragma unroll
      for (int j = 0; j < 8; j++) {
        loc[j] = __hip_atomic_load(&hist[tid * 8 + j], __ATOMIC_RELAXED,
                                   __HIP_MEMORY_SCOPE_AGENT);
        s += loc[j];
      }
      sh[tid] = s; __syncthreads();
      for (int off = 1; off < 256; off <<= 1) {
        uint32_t v = (tid >= off) ? sh[tid - off] : 0u;
        __syncthreads();
        sh[tid] += v;
        __syncthreads();
      }
      uint32_t total = sh[255];
      uint32_t K = total < CAPK ? total : CAPK;
      if (tid == 0) {
        sel[3] = K;
        if (K == 0u) { sel[0] = 0xFFFFFFFFu; sel[1] = 0u; sel[2] = 0u; }
      }
      if (K > 0u) {
        uint32_t myC = sh[tid], pvC = (tid == 0) ? 0u : sh[tid - 1];
        if (myC >= K && pvC < K) {
          uint32_t cum = pvC; int bb = tid * 8;
          for (int j = 0; j < 8; j++) {
            if (cum + loc[j] >= K) { bb = tid * 8 + j; break; }
            cum += loc[j];
          }
          sel[0] = (uint32_t)bb; sel[1] = cum; sel[2] = K - cum;
        }
      }
      __syncthreads();
    }
  }

  grd.sync();

  // ---- Phase C: emit labels + wts from registers; push boundary cands ----
  uint32_t bf = __hip_atomic_load(&ws[F_OFF_SEL + 0], __ATOMIC_RELAXED,
                                  __HIP_MEMORY_SCOPE_AGENT);
  uint32_t Kf = __hip_atomic_load(&ws[F_OFF_SEL + 3], __ATOMIC_RELAXED,
                                  __HIP_MEMORY_SCOPE_AGENT);
  uint32_t bbnd = __hip_atomic_load(&ws[F_OFF_SEL + 4], __ATOMIC_RELAXED,
                                    __HIP_MEMORY_SCOPE_AGENT);
  uint32_t Kb = __hip_atomic_load(&ws[F_OFF_SEL + 7], __ATOMIC_RELAXED,
                                  __HIP_MEMORY_SCOPE_AGENT);
  float inv = 1.0f / (float)(Kf + Kb);   // 1/num_ni
  #pragma unroll
  for (int r = 0; r < 4; r++) {
    int hw = (hb + r) * 256 + w;
    uint32_t lab = lm[r] >> 24;
    uint32_t m = lm[r] & 0x7FFFFFu;
    uint32_t n = (uint32_t)(hw * 9 + a);
    float outv = 2.0f, wv = 0.0f;
    if (lab == LAB_FG) {
      uint32_t bn = m >> BIN_SHIFT;
      if (bn < bf) { outv = 1.0f; wv = inv; }
      else if (bn == bf) {
        uint32_t idx = atomicAdd(&ws[F_OFF_CNTF], 1u);
        if (idx < CAND_CAP)
          ((uint64_t*)(ws + F_OFF_CANDF))[idx] =
              ((uint64_t)m << 20) | (uint64_t)n;
      }
    } else if (lab == LAB_BG) {
      uint32_t bn = m >> BIN_SHIFT;
      if (bn < bbnd) { outv = 0.0f; }
      else if (bn == bbnd) {
        uint32_t idx = atomicAdd(&ws[F_OFF_CNTB], 1u);
        if (idx < CAND_CAP)
          ((uint64_t*)(ws + F_OFF_CANDB))[idx] =
              ((uint64_t)m << 20) | (uint64_t)n;
      }
    }
    out_lab[a * HW + hw] = outv;
    int c4 = a * 4;
    out_wts[(c4 + 0) * HW + hw] = wv;
    out_wts[(c4 + 1) * HW + hw] = wv;
    out_wts[(c4 + 2) * HW + hw] = wv;
    out_wts[(c4 + 3) * HW + hw] = wv;
  }

  grd.sync();

  // ---- Phase D: rank boundary candidates (blocks 0/1), promote rank<need
  if (b < 2) {
    int cls = b;
    uint32_t cnt = __hip_atomic_load(
        &ws[cls == 0 ? F_OFF_CNTF : F_OFF_CNTB], __ATOMIC_RELAXED,
        __HIP_MEMORY_SCOPE_AGENT);
    uint32_t C = cnt < CAND_CAP ? cnt : CAND_CAP;
    uint32_t need = __hip_atomic_load(&ws[F_OFF_SEL + cls * 4 + 2],
                                      __ATOMIC_RELAXED,
                                      __HIP_MEMORY_SCOPE_AGENT);
    const uint64_t* cand =
        (const uint64_t*)(ws + (cls == 0 ? F_OFF_CANDF : F_OFF_CANDB));
    for (uint32_t i = tid; i < C; i += 256)
      SMEM[i] = __hip_atomic_load(&cand[i], __ATOMIC_RELAXED,
                                  __HIP_MEMORY_SCOPE_AGENT);
    __syncthreads();
    for (uint32_t i = tid; i < C; i += 256) {
      uint64_t k = SMEM[i];
      uint32_t rr = 0;
      for (uint32_t j = 0; j < C; j++) rr += (SMEM[j] < k) ? 1u : 0u;
      if (rr < need) {
        uint32_t n = (uint32_t)(k & 0xFFFFFu);
        uint32_t aa = n % 9u, hww = n / 9u;
        uint32_t t = aa * HW + hww;
        if (cls == 0) {
          out_lab[t] = 1.0f;
          #pragma unroll
          for (int j2 = 0; j2 < 4; j2++)
            out_wts[(aa * 4 + j2) * HW + hww] = inv;
        } else {
          out_lab[t] = 0.0f;
        }
      }
    }
  }
}

// ===========================================================================
// Fallback path: proven 4-kernel pipeline (verbatim from Round 3)
// ===========================================================================
__global__ __launch_bounds__(256) void k_gmax(const float* __restrict__ gt,
                                              const int* __restrict__ imw_p,
                                              const int* __restrict__ imh_p,
                                              uint32_t* __restrict__ ws) {
  #pragma clang fp contract(off)
  int tid = threadIdx.x;
  int b = blockIdx.x;
  int gid = b * 256 + tid;
  if (gid < NZ) ws[ZERO_BEG + gid] = 0u;

  int g = b >> 3, sl = b & 7;
  float g0 = gt[g*4+0], g1 = gt[g*4+1], g2 = gt[g*4+2], g3 = gt[g*4+3];
  float gw = g2 - g0 + 1.0f, gh = g3 - g1 + 1.0f;
  float ga = (gw > 0.0f && gh > 0.0f) ? gw * gh : 0.0f;
  float imw = (float)imw_p[0], imh = (float)imh_p[0];

  float mx = 0.0f;
  for (int a = 0; a < NUM_A; a++) {
    float b0 = BA[a][0], b1 = BA[a][1], b2 = BA[a][2], b3 = BA[a][3];
    int wlo = max(0,   (int)floorf((g0 - 1.0f - b2) * 0.0625f));
    int whi = min(255, (int)ceilf ((g2 + 1.0f - b0) * 0.0625f));
    int hlo = max(0,   (int)floorf((g1 - 1.0f - b3) * 0.0625f));
    int hhi = min(255, (int)ceilf ((g3 + 1.0f - b1) * 0.0625f));
    int wx = whi - wlo + 1, wy = hhi - hlo + 1;
    if (wx <= 0 || wy <= 0) continue;
    int tot = wx * wy;
    for (int idx = sl * 256 + tid; idx < tot; idx += 2048) {
      int h = hlo + idx / wx, w = wlo + idx % wx;
      float sx = (float)(w << 4), sy = (float)(h << 4);
      float x1 = b0 + sx, y1 = b1 + sy, x2 = b2 + sx, y2 = b3 + sy;
      float aw = x2 - x1 + 1.0f, ah = y2 - y1 + 1.0f;
      float aarea = aw * ah;
      bool vld = (x1 >= 0.0f) && (y1 >= 0.0f) && (x2 < imw) && (y2 < imh);
      float o = iou1(x1, y1, x2, y2, aarea, g0, g1, g2, g3, ga);
      if (vld) mx = fmaxf(mx, o);
    }
  }
  #pragma unroll
  for (int s = 32; s >= 1; s >>= 1) mx = fmaxf(mx, __shfl_xor(mx, s, 64));
  __shared__ float wmax[4];
  if ((tid & 63) == 0) wmax[tid >> 6] = mx;
  __syncthreads();
  if (tid == 0) {
    float m = fmaxf(fmaxf(wmax[0], wmax[1]), fmaxf(wmax[2], wmax[3]));
    ws[OFF_GMAX8 + g * 8 + sl] = __float_as_uint(m);
  }
}

__global__ __launch_bounds__(256) void k_main(const float* __restrict__ gt,
                                              const int* __restrict__ imw_p,
                                              const int* __restrict__ imh_p,
                                              float* __restrict__ out_adj,
                                              uint32_t* __restrict__ ws,
                                              uint32_t kf0, uint32_t kf1,
                                              uint32_t kb0, uint32_t kb1) {
  #pragma clang fp contract(off)
  __shared__ float sg0[NG], sg1[NG], sg2[NG], sg3[NG], sga[NG], sgm[NG];
  __shared__ uint32_t sh[2 * NBIN];
  __shared__ unsigned long long sMask[4];
  __shared__ int sAnyZero, sLast;
  int tid = threadIdx.x;
  {
    uint4* sh4 = (uint4*)sh;
    #pragma unroll
    for (int k = 0; k < 4; k++) sh4[tid + k * 256] = make_uint4(0, 0, 0, 0);
  }
  if (tid == 0) sAnyZero = 0;
  if (tid < NG) {
    const float4 g4 = ((const float4*)gt)[tid];
    sg0[tid] = g4.x; sg1[tid] = g4.y; sg2[tid] = g4.z; sg3[tid] = g4.w;
    float gw = g4.z - g4.x + 1.0f, gh = g4.w - g4.y + 1.0f;
    sga[tid] = (gw > 0.0f && gh > 0.0f) ? gw * gh : 0.0f;
    uint32_t mm = 0u;
    #pragma unroll
    for (int j = 0; j < 8; j++) mm = max(mm, ws[OFF_GMAX8 + tid * 8 + j]);
    sgm[tid] = __uint_as_float(mm);
    if (mm == 0u) atomicOr(&sAnyZero, 1);
  }
  __syncthreads();

  int b = blockIdx.x;
  int a = b >> 6, hb = (b & 63) << 2;
  float BA0 = BA[a][0], BA1 = BA[a][1], BA2 = BA[a][2], BA3 = BA[a][3];

  {
    int wv = tid >> 6, g = tid & 63;
    float sy = (float)((hb + wv) << 4);
    float ihp = fminf(BA3 + sy, sg3[g]) - fmaxf(BA1 + sy, sg1[g]) + 1.0f;
    unsigned long long mk = __ballot(ihp > 0.0f);
    if (g == 0) sMask[wv] = mk;
  }
  __syncthreads();

  float imw = (float)imw_p[0], imh = (float)imh_p[0];
  int w = tid;
  float sx = (float)(w << 4);
  float A0 = BA0 + sx, A2 = BA2 + sx;
  float aw = A2 - A0 + 1.0f;
  float A1v[4], A3v[4];
  #pragma unroll
  for (int r = 0; r < 4; r++) {
    float sy = (float)((hb + r) << 4);
    A1v[r] = BA1 + sy; A3v[r] = BA3 + sy;
  }
  float ah = A3v[0] - A1v[0] + 1.0f;
  float aarea = aw * ah;
  bool xv = (A0 >= 0.0f) && (A2 < imw);

  unsigned long long mk0 = sMask[0], mk1 = sMask[1],
                     mk2 = sMask[2], mk3 = sMask[3];
  unsigned long long uni = mk0 | mk1 | mk2 | mk3;
  float amaxv[4] = {0.f, 0.f, 0.f, 0.f};
  int bgv[4] = {0, 0, 0, 0};
  uint32_t afv = 0u;
  while (uni) {
    int g = __ffsll(uni) - 1;
    uni &= uni - 1;
    float iw = fminf(A2, sg2[g]) - fmaxf(A0, sg0[g]) + 1.0f;
    if (!__any(iw > 0.0f)) continue;
    if (iw > 0.0f) {
      float base = aarea + sga[g];
      float gy1 = sg1[g], gy2 = sg3[g], gm = sgm[g];
#define DO_ROW(r, mk)                                                     \
      if ((mk >> g) & 1ull) {                                             \
        float ih = fminf(A3v[r], gy2) - fmaxf(A1v[r], gy1) + 1.0f;        \
        float inter = iw * ih;                                            \
        float o = inter / (base - inter);                                 \
        if (o > amaxv[r]) { amaxv[r] = o; bgv[r] = g; }                   \
        if (o == gm) afv |= (1u << r);                                    \
      }
      DO_ROW(0, mk0) DO_ROW(1, mk1) DO_ROW(2, mk2) DO_ROW(3, mk3)
#undef DO_ROW
    }
  }

  bool anyZ = (sAnyZero != 0);
  #pragma unroll
  for (int r = 0; r < 4; r++) {
    int hw = (hb + r) * 256 + w;
    bool valid = xv && (A1v[r] >= 0.0f) && (A3v[r] < imh);
    float amax = amaxv[r];
    bool anyfg = (((afv >> r) & 1u) || anyZ) && valid;
    uint32_t lab;
    if (!valid)                       lab = LAB_IGN;
    else if (anyfg || amax >= 0.7f)   lab = LAB_FG;
    else if (amax < 0.3f)             lab = LAB_BG;
    else                              lab = LAB_IGN;

    float adj0 = 0.f, adj1 = 0.f, adj2 = 0.f, adj3 = 0.f;
    if (valid) {
      int bg = bgv[r];
      float G0 = sg0[bg], G1 = sg1[bg], G2 = sg2[bg], G3 = sg3[bg];
      float ax = (A2 + A0) * 0.5f, ay = (A3v[r] + A1v[r]) * 0.5f;
      float gwm = G2 - G0 + 1.0f, ghm = G3 - G1 + 1.0f;
      float gx = (G2 + G0) * 0.5f, gy = (G3 + G1) * 0.5f;
      adj0 = (gx - ax) / aw;
      adj1 = (gy - ay) / ah;
      adj2 = logf(gwm / aw);
      adj3 = logf(ghm / ah);
    }
    int c4 = a * 4;
    out_adj[(c4 + 0) * HW + hw] = adj0;
    out_adj[(c4 + 1) * HW + hw] = adj1;
    out_adj[(c4 + 2) * HW + hw] = adj2;
    out_adj[(c4 + 3) * HW + hw] = adj3;

    uint32_t m = 0u;
    uint32_t n = (uint32_t)(hw * 9 + a);
    if (lab != LAB_IGN) {
      uint32_t kk0 = (lab == LAB_FG) ? kf0 : kb0;
      uint32_t kk1 = (lab == LAB_FG) ? kf1 : kb1;
      m = mant_of(kk0, kk1, n);
      atomicAdd(&sh[((lab == LAB_FG) ? 0 : NBIN) + (m >> BIN_SHIFT)], 1u);
    }
    ws[OFF_LABM + a * HW + hw] = (lab << 24) | m;
  }

  __syncthreads();
  for (int i = tid; i < 2 * NBIN; i += 256) {
    uint32_t v = sh[i];
    if (v) atomicAdd(&ws[OFF_HF + i], v);
  }
  __syncthreads();
  if (tid == 0)
    sLast = (atomicAdd(&ws[OFF_DONE2], 1u) == 575u) ? 1 : 0;
  __syncthreads();
  if (sLast) {
    for (int cls = 0; cls < 2; cls++) {
      uint32_t* hist = ws + (cls ? OFF_HB : OFF_HF);
      uint32_t* sel = ws + OFF_SEL + cls * 4;
      uint32_t loc[8], s = 0;
      #pragma unroll
      for (int j = 0; j < 8; j++) {
        loc[j] = __hip_atomic_load(&hist[tid * 8 + j], __ATOMIC_RELAXED,
                                   __HIP_MEMORY_SCOPE_AGENT);
        s += loc[j];
      }
      sh[tid] = s; __syncthreads();
      for (int off = 1; off < 256; off <<= 1) {
        uint32_t v = (tid >= off) ? sh[tid - off] : 0u;
        __syncthreads();
        sh[tid] += v;
        __syncthreads();
      }
      uint32_t total = sh[255];
      uint32_t K = total < CAPK ? total : CAPK;
      if (tid == 0) {
        sel[3] = K;
        if (K == 0u) { sel[0] = 0xFFFFFFFFu; sel[1] = 0u; sel[2] = 0u; }
      }
      if (K > 0u) {
        uint32_t myC = sh[tid], pvC = (tid == 0) ? 0u : sh[tid - 1];
        if (myC >= K && pvC < K) {
          uint32_t cum = pvC; int bb = tid * 8;
          for (int j = 0; j < 8; j++) {
            if (cum + loc[j] >= K) { bb = tid * 8 + j; break; }
            cum += loc[j];
          }
          sel[0] = (uint32_t)bb; sel[1] = cum; sel[2] = K - cum;
        }
      }
      __syncthreads();
    }
  }
}

__global__ __launch_bounds__(256) void k_emit(float* __restrict__ out_lab,
                                              float* __restrict__ out_wts,
                                              uint32_t* __restrict__ ws) {
  int t = blockIdx.x * 256 + threadIdx.x;
  uint32_t lm = ws[OFF_LABM + t];
  uint32_t lab = lm >> 24;
  uint32_t m = lm & 0x7FFFFFu;
  uint32_t Kf = ws[OFF_SEL + 3], Kb = ws[OFF_SEL + 7];
  float inv = 1.0f / (float)(Kf + Kb);
  int a = t >> 16, hw = t & 65535;
  uint32_t n = (uint32_t)(hw * 9 + a);

  float outv = 2.0f, wv = 0.0f;
  if (lab == LAB_FG) {
    uint32_t b = m >> BIN_SHIFT, bf = ws[OFF_SEL + 0];
    if (b < bf) { outv = 1.0f; wv = inv; }
    else if (b == bf) {
      uint32_t idx = atomicAdd(&ws[OFF_CNTF], 1u);
      if (idx < CAND_CAP)
        ((uint64_t*)(ws + OFF_CANDF))[idx] = ((uint64_t)m << 20) | (uint64_t)n;
    }
  } else if (lab == LAB_BG) {
    uint32_t b = m >> BIN_SHIFT, bb = ws[OFF_SEL + 4];
    if (b < bb) { outv = 0.0f; }
    else if (b == bb) {
      uint32_t idx = atomicAdd(&ws[OFF_CNTB], 1u);
      if (idx < CAND_CAP)
        ((uint64_t*)(ws + OFF_CANDB))[idx] = ((uint64_t)m << 20) | (uint64_t)n;
    }
  }
  out_lab[t] = outv;
  int c4 = a * 4;
  out_wts[(c4 + 0) * HW + hw] = wv;
  out_wts[(c4 + 1) * HW + hw] = wv;
  out_wts[(c4 + 2) * HW + hw] = wv;
  out_wts[(c4 + 3) * HW + hw] = wv;
}

__global__ __launch_bounds__(256) void k_fixup(float* __restrict__ out_lab,
                                               float* __restrict__ out_wts,
                                               uint32_t* __restrict__ ws) {
  __shared__ uint64_t sc[CAND_CAP];
  int cls = blockIdx.x;
  uint32_t cnt = ws[cls == 0 ? OFF_CNTF : OFF_CNTB];
  uint32_t C = cnt < CAND_CAP ? cnt : CAND_CAP;
  uint32_t need = ws[OFF_SEL + cls * 4 + 2];
  uint32_t Kf = ws[OFF_SEL + 3], Kb = ws[OFF_SEL + 7];
  float inv = 1.0f / (float)(Kf + Kb);
  const uint64_t* cand =
      (const uint64_t*)(ws + (cls == 0 ? OFF_CANDF : OFF_CANDB));
  for (uint32_t i = threadIdx.x; i < C; i += 256) sc[i] = cand[i];
  __syncthreads();
  for (uint32_t i = threadIdx.x; i < C; i += 256) {
    uint64_t k = sc[i];
    uint32_t r = 0;
    for (uint32_t j = 0; j < C; j++) r += (sc[j] < k) ? 1u : 0u;
    if (r < need) {
      uint32_t n = (uint32_t)(k & 0xFFFFFu);
      uint32_t a = n % 9u, hw = n / 9u;
      uint32_t t = a * HW + hw;
      if (cls == 0) {
        out_lab[t] = 1.0f;
        #pragma unroll
        for (int j = 0; j < 4; j++) out_wts[(a * 4 + j) * HW + hw] = inv;
      } else {
        out_lab[t] = 0.0f;
      }
    }
  }
}

extern "C" void kernel_launch(void* const* d_in, const int* in_sizes, int n_in,
                              void* d_out, int out_size, void* d_ws,
                              size_t ws_size, hipStream_t stream) {
  const float* gt  = (const float*)d_in[1];
  const int*   imw = (const int*)d_in[2];
  const int*   imh = (const int*)d_in[3];
  float* out      = (float*)d_out;
  float* out_lab  = out;
  float* out_adj  = out + N_ANCH;
  float* out_wts  = out + 5 * N_ANCH;
  uint32_t* ws = (uint32_t*)d_ws;

  uint32_t kf0, kf1, kb0, kb1;
  tf2x32(0u, 42u, 0u, 0u, &kf0, &kf1);
  tf2x32(0u, 42u, 0u, 1u, &kb0, &kb1);

  void* kargs[] = {(void*)&gt,      (void*)&imw,     (void*)&imh,
                   (void*)&out_lab, (void*)&out_adj, (void*)&out_wts,
                   (void*)&ws,      (void*)&kf0,     (void*)&kf1,
                   (void*)&kb0,     (void*)&kb1};
  hipError_t err = hipLaunchCooperativeKernel(
      (const void*)k_fused, dim3(576), dim3(256), kargs, 0, stream);
  if (err != hipSuccess) {
    (void)hipGetLastError();  // clear sticky error; fall back to 4-kernel path
    hipLaunchKernelGGL(k_gmax, dim3(NG * 8), dim3(256), 0, stream, gt, imw,
                       imh, ws);
    hipLaunchKernelGGL(k_main, dim3(576), dim3(256), 0, stream, gt, imw, imh,
                       out_adj, ws, kf0, kf1, kb0, kb1);
    hipLaunchKernelGGL(k_emit, dim3(N_ANCH / 256), dim3(256), 0, stream,
                       out_lab, out_wts, ws);
    hipLaunchKernelGGL(k_fixup, dim3(2), dim3(256), 0, stream, out_lab,
                       out_wts, ws);
  }
}

// Round 2
// 156.560 us; speedup vs baseline: 1.9694x; 1.9694x over previous
//
#include <hip/hip_runtime.h>
#include <stdint.h>

// ===========================================================================
// AnchorDataGenerator (Faster R-CNN anchor target layer), MI355X / gfx950
// Round 5: back to non-cooperative dispatches (grid.sync cost ~70us/barrier
// on 8-XCD MI355X -> refuted). Structure:
//   memset(16.4KB ctrl)                      [hipMemsetAsync, ~3us]
//   k_main2 (576 blocks): LOCAL analytic gmax (no k_gmax kernel!), main IoU
//     pass, labels/adj/mantissa/hist, done-counter last block -> select.
//   k_emit2 (2304 blocks): emit labels/wts + boundary candidate push;
//     done-counter last block runs the O(C^2) fixup (k_fixup fused away).
// Analytic gmax: IoU monotone in inter=iw*ih; iw depends only on x-shift,
// ih only on y-shift; validity separable; iw(w) concave -> max over valid
// grid at clamped floor/ceil of continuous argmax. ~6 candidates/axis,
// exact same fp op order as reference -> bit-exact.
// ===========================================================================

#define NUM_A 9
#define HW 65536
#define N_ANCH 589824
#define NG 64
#define CAPK 128u
#define NBIN 2048
#define BIN_SHIFT 12
#define CAND_CAP 4096

#define LAB_BG 0u
#define LAB_FG 1u
#define LAB_IGN 2u

// workspace layout (u32 units)
#define OFF_HF    0
#define OFF_HB    NBIN                       // 2048
#define OFF_CNTF  (2*NBIN)                   // 4096
#define OFF_CNTB  (OFF_CNTF + 1)             // 4097
#define OFF_DONE  (OFF_CNTF + 2)             // 4098 (k_main2 select counter)
#define OFF_DONE2 (OFF_CNTF + 3)             // 4099 (k_emit2 fixup counter)
#define OFF_SEL   (OFF_CNTF + 4)             // 4100..4107 {bin,below,need,K}x2
#define CTRL_WORDS 4108                      // memset range
#define OFF_CANDF 4108                       // byte 16432, 8B aligned
#define OFF_CANDB (OFF_CANDF + 2*CAND_CAP)   // 12300
#define OFF_LABM  (OFF_CANDB + 2*CAND_CAP)   // 20492

#define NBLK_MAIN 576
#define NBLK_EMIT (N_ANCH / 256)             // 2304

__constant__ float BA[NUM_A][4] = {
  { -84.f,  -40.f,  99.f,  55.f}, {-176.f,  -88.f, 191.f, 103.f},
  {-360.f, -184.f, 375.f, 199.f}, { -56.f,  -56.f,  71.f,  71.f},
  {-120.f, -120.f, 135.f, 135.f}, {-248.f, -248.f, 263.f, 263.f},
  { -36.f,  -80.f,  51.f,  95.f}, { -80.f, -168.f,  95.f, 183.f},
  {-168.f, -344.f, 183.f, 359.f}};

__host__ __device__ static inline void tf2x32(uint32_t k0, uint32_t k1,
                                              uint32_t x0, uint32_t x1,
                                              uint32_t* o0, uint32_t* o1) {
  const uint32_t ks2 = k0 ^ k1 ^ 0x1BD11BDAu;
#define TF_R(r) { x0 += x1; x1 = (x1 << (r)) | (x1 >> (32 - (r))); x1 ^= x0; }
  x0 += k0; x1 += k1;
  TF_R(13) TF_R(15) TF_R(26) TF_R(6)
  x0 += k1;  x1 += ks2 + 1u;
  TF_R(17) TF_R(29) TF_R(16) TF_R(24)
  x0 += ks2; x1 += k0 + 2u;
  TF_R(13) TF_R(15) TF_R(26) TF_R(6)
  x0 += k0;  x1 += k1 + 3u;
  TF_R(17) TF_R(29) TF_R(16) TF_R(24)
  x0 += k1;  x1 += ks2 + 4u;
  TF_R(13) TF_R(15) TF_R(26) TF_R(6)
  x0 += ks2; x1 += k0 + 5u;
#undef TF_R
  *o0 = x0; *o1 = x1;
}

__device__ static inline uint32_t mant_of(uint32_t k0, uint32_t k1, uint32_t n) {
  uint32_t o0, o1;
  tf2x32(k0, k1, 0u, n, &o0, &o1);   // partitionable: counter = (hi=0, lo=n)
  return (o0 ^ o1) >> 9;             // 23-bit mantissa
}

// Max of fl(iw) over valid integer shifts [lo,hi] for one axis.
// iw(w) = fminf(bhi+16w, ghi) - fmaxf(blo+16w, glo) + 1 is concave in w
// (min-affine minus max-affine); fl monotone => unimodal. Max over the grid
// is at clamped floor/ceil of the continuous argmax interval endpoints.
__device__ static inline float axis_best(float blo, float bhi, float glo,
                                         float ghi, int lo, int hi) {
  #pragma clang fp contract(off)
  float t1 = (ghi - bhi) * 0.0625f;
  float t2 = (glo - blo) * 0.0625f;
  float tmin = fminf(t1, t2), tmax = fmaxf(t1, t2);
  int c1 = (int)floorf(tmin), c2 = (int)ceilf(tmax);
  int cand0 = lo, cand1 = hi;
  int cand2 = min(max(c1,     lo), hi);
  int cand3 = min(max(c1 + 1, lo), hi);
  int cand4 = min(max(c2 - 1, lo), hi);
  int cand5 = min(max(c2,     lo), hi);
  float best = -3.0e38f;
  int cands[6] = {cand0, cand1, cand2, cand3, cand4, cand5};
  #pragma unroll
  for (int i = 0; i < 6; i++) {
    float s = (float)(cands[i] << 4);
    float v = fminf(bhi + s, ghi) - fmaxf(blo + s, glo) + 1.0f;
    best = fmaxf(best, v);
  }
  return best;
}

// ---- main pass: local analytic gmax + labels/adj/mantissa/hist + select ---
__global__ __launch_bounds__(256) void k_main2(const float* __restrict__ gt,
                                               const int* __restrict__ imw_p,
                                               const int* __restrict__ imh_p,
                                               float* __restrict__ out_adj,
                                               uint32_t* __restrict__ ws,
                                               uint32_t kf0, uint32_t kf1,
                                               uint32_t kb0, uint32_t kb1) {
  #pragma clang fp contract(off)
  __shared__ float sg0[NG], sg1[NG], sg2[NG], sg3[NG], sga[NG], sgm[NG];
  __shared__ uint32_t sgmU[NG];
  __shared__ uint32_t sh[2 * NBIN];
  __shared__ unsigned long long sMask[4];
  __shared__ int sAnyZero, sLast;
  int tid = threadIdx.x;
  int b = blockIdx.x;
  int a = b >> 6, hb = (b & 63) << 2;      // anchor type, 4 rows hb..hb+3
  {
    uint4* sh4 = (uint4*)sh;
    #pragma unroll
    for (int k = 0; k < 4; k++) sh4[tid + k * 256] = make_uint4(0, 0, 0, 0);
  }
  if (tid == 0) sAnyZero = 0;
  if (tid < NG) {
    const float4 g4 = ((const float4*)gt)[tid];
    sg0[tid] = g4.x; sg1[tid] = g4.y; sg2[tid] = g4.z; sg3[tid] = g4.w;
    float gw = g4.z - g4.x + 1.0f, gh = g4.w - g4.y + 1.0f;
    sga[tid] = (gw > 0.0f && gh > 0.0f) ? gw * gh : 0.0f;
    sgmU[tid] = 0u;
  }
  __syncthreads();   // S1: gt staged, sgmU zeroed

  // local gmax: 576 (gt,type) pairs over 256 threads; LDS atomicMax on
  // float bits (IoU >= 0 -> bit order == float order).
  {
    int imwi = imw_p[0], imhi = imh_p[0];
    for (int p = tid; p < NG * NUM_A; p += 256) {
      int g = p / NUM_A, q = p - g * NUM_A;
      float b0 = BA[q][0], b1 = BA[q][1], b2 = BA[q][2], b3 = BA[q][3];
      int ib0 = (int)b0, ib1 = (int)b1, ib2 = (int)b2, ib3 = (int)b3;
      int wlo = max(0, (-ib0 + 15) >> 4);
      int whi = min(255, (imwi - ib2 - 1) >> 4);
      int hlo = max(0, (-ib1 + 15) >> 4);
      int hhi = min(255, (imhi - ib3 - 1) >> 4);
      if (wlo > whi || hlo > hhi) continue;   // no valid anchor of this type
      float iwb = axis_best(b0, b2, sg0[g], sg2[g], wlo, whi);
      float ihb = axis_best(b1, b3, sg1[g], sg3[g], hlo, hhi);
      float aw = b2 - b0 + 1.0f, ah = b3 - b1 + 1.0f;
      float aarea = aw * ah;
      float inter = (iwb > 0.0f && ihb > 0.0f) ? iwb * ihb : 0.0f;
      float den = aarea + sga[g] - inter;
      float o = inter / den;
      atomicMax(&sgmU[g], __float_as_uint(o));
    }
  }

  // per-wave y-mask: wave r handles row hb+r; lane = gt index
  {
    int wv = tid >> 6, g = tid & 63;
    float sy = (float)((hb + wv) << 4);
    float ihp = fminf(BA[a][3] + sy, sg3[g]) - fmaxf(BA[a][1] + sy, sg1[g]) + 1.0f;
    unsigned long long mk = __ballot(ihp > 0.0f);
    if (g == 0) sMask[wv] = mk;
  }
  __syncthreads();   // S2: sgmU final, sMask ready
  if (tid < NG) {
    uint32_t mm = sgmU[tid];
    sgm[tid] = __uint_as_float(mm);
    if (mm == 0u) atomicOr(&sAnyZero, 1);
  }
  __syncthreads();   // S3: sgm, sAnyZero ready

  float BA0 = BA[a][0], BA1 = BA[a][1], BA2 = BA[a][2], BA3 = BA[a][3];
  float imw = (float)imw_p[0], imh = (float)imh_p[0];
  int w = tid;
  float sx = (float)(w << 4);
  float A0 = BA0 + sx, A2 = BA2 + sx;
  float aw = A2 - A0 + 1.0f;
  float A1v[4], A3v[4];
  #pragma unroll
  for (int r = 0; r < 4; r++) {
    float sy = (float)((hb + r) << 4);
    A1v[r] = BA1 + sy; A3v[r] = BA3 + sy;
  }
  float ah = A3v[0] - A1v[0] + 1.0f;
  float aarea = aw * ah;                   // exact ints -> bit-exact
  bool xv = (A0 >= 0.0f) && (A2 < imw);

  unsigned long long mk0 = sMask[0], mk1 = sMask[1],
                     mk2 = sMask[2], mk3 = sMask[3];
  unsigned long long uni = mk0 | mk1 | mk2 | mk3;
  float amaxv[4] = {0.f, 0.f, 0.f, 0.f};
  int bgv[4] = {0, 0, 0, 0};
  uint32_t afv = 0u;
  while (uni) {
    int g = __ffsll(uni) - 1;
    uni &= uni - 1;
    float iw = fminf(A2, sg2[g]) - fmaxf(A0, sg0[g]) + 1.0f;
    if (!__any(iw > 0.0f)) continue;
    if (iw > 0.0f) {
      float base = aarea + sga[g];
      float gy1 = sg1[g], gy2 = sg3[g], gm = sgm[g];
#define DO_ROW(r, mk)                                                     \
      if ((mk >> g) & 1ull) {                                             \
        float ih = fminf(A3v[r], gy2) - fmaxf(A1v[r], gy1) + 1.0f;        \
        float inter = iw * ih;                                            \
        float o = inter / (base - inter);                                 \
        if (o > amaxv[r]) { amaxv[r] = o; bgv[r] = g; }                   \
        if (o == gm) afv |= (1u << r);                                    \
      }
      DO_ROW(0, mk0) DO_ROW(1, mk1) DO_ROW(2, mk2) DO_ROW(3, mk3)
#undef DO_ROW
    }
  }

  bool anyZ = (sAnyZero != 0);
  #pragma unroll
  for (int r = 0; r < 4; r++) {
    int hw = (hb + r) * 256 + w;
    bool valid = xv && (A1v[r] >= 0.0f) && (A3v[r] < imh);
    float amax = amaxv[r];
    bool anyfg = (((afv >> r) & 1u) || anyZ) && valid;
    uint32_t lab;
    if (!valid)                       lab = LAB_IGN;
    else if (anyfg || amax >= 0.7f)   lab = LAB_FG;
    else if (amax < 0.3f)             lab = LAB_BG;
    else                              lab = LAB_IGN;

    float adj0 = 0.f, adj1 = 0.f, adj2 = 0.f, adj3 = 0.f;
    if (valid) {
      int bg = bgv[r];
      float G0 = sg0[bg], G1 = sg1[bg], G2 = sg2[bg], G3 = sg3[bg];
      float ax = (A2 + A0) * 0.5f, ay = (A3v[r] + A1v[r]) * 0.5f;
      float gwm = G2 - G0 + 1.0f, ghm = G3 - G1 + 1.0f;
      float gx = (G2 + G0) * 0.5f, gy = (G3 + G1) * 0.5f;
      adj0 = (gx - ax) / aw;
      adj1 = (gy - ay) / ah;
      adj2 = logf(gwm / aw);
      adj3 = logf(ghm / ah);
    }
    int c4 = a * 4;
    out_adj[(c4 + 0) * HW + hw] = adj0;
    out_adj[(c4 + 1) * HW + hw] = adj1;
    out_adj[(c4 + 2) * HW + hw] = adj2;
    out_adj[(c4 + 3) * HW + hw] = adj3;

    uint32_t m = 0u;
    uint32_t n = (uint32_t)(hw * 9 + a);   // original anchor index (tie-break)
    if (lab != LAB_IGN) {
      uint32_t kk0 = (lab == LAB_FG) ? kf0 : kb0;
      uint32_t kk1 = (lab == LAB_FG) ? kf1 : kb1;
      m = mant_of(kk0, kk1, n);
      atomicAdd(&sh[((lab == LAB_FG) ? 0 : NBIN) + (m >> BIN_SHIFT)], 1u);
    }
    ws[OFF_LABM + a * HW + hw] = (lab << 24) | m;
  }

  __syncthreads();
  for (int i = tid; i < 2 * NBIN; i += 256) {
    uint32_t v = sh[i];
    if (v) atomicAdd(&ws[OFF_HF + i], v);
  }
  __syncthreads();
  if (tid == 0)
    sLast = (atomicAdd(&ws[OFF_DONE], 1u) == NBLK_MAIN - 1) ? 1 : 0;
  __syncthreads();
  if (sLast) {
    // select: histogram CDF -> subsample boundary per class
    for (int cls = 0; cls < 2; cls++) {
      uint32_t* hist = ws + (cls ? OFF_HB : OFF_HF);
      uint32_t* sel = ws + OFF_SEL + cls * 4;
      uint32_t loc[8], s = 0;
      #pragma unroll
      for (int j = 0; j < 8; j++) {
        loc[j] = __hip_atomic_load(&hist[tid * 8 + j], __ATOMIC_RELAXED,
                                   __HIP_MEMORY_SCOPE_AGENT);
        s += loc[j];
      }
      sh[tid] = s; __syncthreads();
      for (int off = 1; off < 256; off <<= 1) {
        uint32_t v = (tid >= off) ? sh[tid - off] : 0u;
        __syncthreads();
        sh[tid] += v;
        __syncthreads();
      }
      uint32_t total = sh[255];
      uint32_t K = total < CAPK ? total : CAPK;
      if (tid == 0) {
        sel[3] = K;
        if (K == 0u) { sel[0] = 0xFFFFFFFFu; sel[1] = 0u; sel[2] = 0u; }
      }
      if (K > 0u) {
        uint32_t myC = sh[tid], pvC = (tid == 0) ? 0u : sh[tid - 1];
        if (myC >= K && pvC < K) {
          uint32_t cum = pvC; int bb = tid * 8;
          for (int j = 0; j < 8; j++) {
            if (cum + loc[j] >= K) { bb = tid * 8 + j; break; }
            cum += loc[j];
          }
          sel[0] = (uint32_t)bb; sel[1] = cum; sel[2] = K - cum;
        }
      }
      __syncthreads();
    }
  }
}

// ---- emit labels + wts; boundary candidates; last block runs fixup --------
__global__ __launch_bounds__(256) void k_emit2(float* __restrict__ out_lab,
                                               float* __restrict__ out_wts,
                                               uint32_t* __restrict__ ws) {
  __shared__ uint64_t sc[CAND_CAP];        // 32 KB (used by last block only)
  __shared__ int sLast;
  int tid = threadIdx.x;
  int t = blockIdx.x * 256 + tid;
  uint32_t lm = ws[OFF_LABM + t];
  uint32_t lab = lm >> 24;
  uint32_t m = lm & 0x7FFFFFu;
  uint32_t Kf = ws[OFF_SEL + 3], Kb = ws[OFF_SEL + 7];
  float inv = 1.0f / (float)(Kf + Kb);     // 1/num_ni
  int a = t >> 16, hw = t & 65535;
  uint32_t n = (uint32_t)(hw * 9 + a);

  float outv = 2.0f, wv = 0.0f;
  if (lab == LAB_FG) {
    uint32_t bn = m >> BIN_SHIFT, bf = ws[OFF_SEL + 0];
    if (bn < bf) { outv = 1.0f; wv = inv; }
    else if (bn == bf) {
      uint32_t idx = atomicAdd(&ws[OFF_CNTF], 1u);
      if (idx < CAND_CAP)
        __hip_atomic_store((uint64_t*)(ws + OFF_CANDF) + idx,
                           ((uint64_t)m << 20) | (uint64_t)n,
                           __ATOMIC_RELAXED, __HIP_MEMORY_SCOPE_AGENT);
    }
  } else if (lab == LAB_BG) {
    uint32_t bn = m >> BIN_SHIFT, bb = ws[OFF_SEL + 4];
    if (bn < bb) { outv = 0.0f; }
    else if (bn == bb) {
      uint32_t idx = atomicAdd(&ws[OFF_CNTB], 1u);
      if (idx < CAND_CAP)
        __hip_atomic_store((uint64_t*)(ws + OFF_CANDB) + idx,
                           ((uint64_t)m << 20) | (uint64_t)n,
                           __ATOMIC_RELAXED, __HIP_MEMORY_SCOPE_AGENT);
    }
  }
  out_lab[t] = outv;
  int c4 = a * 4;
  out_wts[(c4 + 0) * HW + hw] = wv;
  out_wts[(c4 + 1) * HW + hw] = wv;
  out_wts[(c4 + 2) * HW + hw] = wv;
  out_wts[(c4 + 3) * HW + hw] = wv;

  // done-counter: ACQ_REL makes each block's prior stores agent-visible
  // before the last block (acquire side) starts the fixup overwrites.
  __syncthreads();
  if (tid == 0)
    sLast = (__hip_atomic_fetch_add(&ws[OFF_DONE2], 1u, __ATOMIC_ACQ_REL,
                                    __HIP_MEMORY_SCOPE_AGENT)
             == NBLK_EMIT - 1) ? 1 : 0;
  __syncthreads();
  if (sLast) {
    for (int cls = 0; cls < 2; cls++) {
      uint32_t cnt = __hip_atomic_load(&ws[cls == 0 ? OFF_CNTF : OFF_CNTB],
                                       __ATOMIC_RELAXED,
                                       __HIP_MEMORY_SCOPE_AGENT);
      uint32_t C = cnt < CAND_CAP ? cnt : CAND_CAP;
      uint32_t need = ws[OFF_SEL + cls * 4 + 2];
      const uint64_t* cand =
          (const uint64_t*)(ws + (cls == 0 ? OFF_CANDF : OFF_CANDB));
      for (uint32_t i = tid; i < C; i += 256)
        sc[i] = __hip_atomic_load(&cand[i], __ATOMIC_RELAXED,
                                  __HIP_MEMORY_SCOPE_AGENT);
      __syncthreads();
      for (uint32_t i = tid; i < C; i += 256) {
        uint64_t k = sc[i];
        uint32_t rr = 0;
        for (uint32_t j = 0; j < C; j++) rr += (sc[j] < k) ? 1u : 0u;
        if (rr < need) {                   // keys unique -> exactly need kept
          uint32_t nn = (uint32_t)(k & 0xFFFFFu);
          uint32_t aa = nn % 9u, hww = nn / 9u;
          uint32_t tt = aa * HW + hww;
          if (cls == 0) {
            out_lab[tt] = 1.0f;
            #pragma unroll
            for (int j2 = 0; j2 < 4; j2++)
              out_wts[(aa * 4 + j2) * HW + hww] = inv;
          } else {
            out_lab[tt] = 0.0f;
          }
        }
      }
      __syncthreads();
    }
  }
}

extern "C" void kernel_launch(void* const* d_in, const int* in_sizes, int n_in,
                              void* d_out, int out_size, void* d_ws,
                              size_t ws_size, hipStream_t stream) {
  const float* gt  = (const float*)d_in[1];
  const int*   imw = (const int*)d_in[2];
  const int*   imh = (const int*)d_in[3];
  float* out      = (float*)d_out;
  float* out_lab  = out;                   // 589824
  float* out_adj  = out + N_ANCH;          // 4*589824
  float* out_wts  = out + 5 * N_ANCH;      // 4*589824
  uint32_t* ws = (uint32_t*)d_ws;          // ~2.44 MB used

  uint32_t kf0, kf1, kb0, kb1;
  tf2x32(0u, 42u, 0u, 0u, &kf0, &kf1);
  tf2x32(0u, 42u, 0u, 1u, &kb0, &kb1);

  hipMemsetAsync(ws, 0, CTRL_WORDS * sizeof(uint32_t), stream);
  hipLaunchKernelGGL(k_main2, dim3(NBLK_MAIN), dim3(256), 0, stream, gt, imw,
                     imh, out_adj, ws, kf0, kf1, kb0, kb1);
  hipLaunchKernelGGL(k_emit2, dim3(NBLK_EMIT), dim3(256), 0, stream, out_lab,
                     out_wts, ws);
}

// Round 4
// 147.087 us; speedup vs baseline: 2.0962x; 1.0644x over previous
//
#include <hip/hip_runtime.h>
#include <stdint.h>

// ===========================================================================
// AnchorDataGenerator (Faster R-CNN anchor target layer), MI355X / gfx950
// Round 7 (= Round 6 resubmit after infra failure; audit found no fault path):
//   memset(16.4KB ctrl)                       [hipMemsetAsync]
//   k_main2 (576 blocks): analytic local gmax + main IoU pass + hist +
//     done-counter select (proven in Round 5 bench).
//   k_emitfix (2304 blocks): emit labels/wts; boundary-bin anchors are NOT
//     written here (disjoint-writer trick) — pushed as candidates via
//     agent-scope ATOMIC stores (performed at IF, no fence needed).
//     All threads drain vmcnt (wave-local, cheap), then RELAXED done-counter;
//     last block ranks candidates in LDS and is the SOLE writer of candidate
//     anchors' outputs (atomic stores). NO agent-scope acquire/release
//     cache-maintenance anywhere (the 74us lesson from Round 5's k_emit2).
// ===========================================================================

#define NUM_A 9
#define HW 65536
#define N_ANCH 589824
#define NG 64
#define CAPK 128u
#define NBIN 2048
#define BIN_SHIFT 12
#define CAND_CAP 2048

#define LAB_BG 0u
#define LAB_FG 1u
#define LAB_IGN 2u

// workspace layout (u32 units)
#define OFF_HF    0
#define OFF_HB    NBIN                       // 2048
#define OFF_CNTF  (2*NBIN)                   // 4096
#define OFF_CNTB  (OFF_CNTF + 1)             // 4097
#define OFF_DONE  (OFF_CNTF + 2)             // 4098 (k_main2 select counter)
#define OFF_DONE2 (OFF_CNTF + 3)             // 4099 (k_emitfix fixup counter)
#define OFF_SEL   (OFF_CNTF + 4)             // 4100..4107 {bin,below,need,K}x2
#define CTRL_WORDS 4108                      // memset range
#define OFF_CANDF 4108                       // byte 16432, 8B aligned
#define OFF_CANDB (OFF_CANDF + 2*CAND_CAP)   // 8204
#define OFF_LABM  (OFF_CANDB + 2*CAND_CAP)   // 12300

#define NBLK_MAIN 576
#define NBLK_EMIT (N_ANCH / 256)             // 2304

__constant__ float BA[NUM_A][4] = {
  { -84.f,  -40.f,  99.f,  55.f}, {-176.f,  -88.f, 191.f, 103.f},
  {-360.f, -184.f, 375.f, 199.f}, { -56.f,  -56.f,  71.f,  71.f},
  {-120.f, -120.f, 135.f, 135.f}, {-248.f, -248.f, 263.f, 263.f},
  { -36.f,  -80.f,  51.f,  95.f}, { -80.f, -168.f,  95.f, 183.f},
  {-168.f, -344.f, 183.f, 359.f}};

__host__ __device__ static inline void tf2x32(uint32_t k0, uint32_t k1,
                                              uint32_t x0, uint32_t x1,
                                              uint32_t* o0, uint32_t* o1) {
  const uint32_t ks2 = k0 ^ k1 ^ 0x1BD11BDAu;
#define TF_R(r) { x0 += x1; x1 = (x1 << (r)) | (x1 >> (32 - (r))); x1 ^= x0; }
  x0 += k0; x1 += k1;
  TF_R(13) TF_R(15) TF_R(26) TF_R(6)
  x0 += k1;  x1 += ks2 + 1u;
  TF_R(17) TF_R(29) TF_R(16) TF_R(24)
  x0 += ks2; x1 += k0 + 2u;
  TF_R(13) TF_R(15) TF_R(26) TF_R(6)
  x0 += k0;  x1 += k1 + 3u;
  TF_R(17) TF_R(29) TF_R(16) TF_R(24)
  x0 += k1;  x1 += ks2 + 4u;
  TF_R(13) TF_R(15) TF_R(26) TF_R(6)
  x0 += ks2; x1 += k0 + 5u;
#undef TF_R
  *o0 = x0; *o1 = x1;
}

__device__ static inline uint32_t mant_of(uint32_t k0, uint32_t k1, uint32_t n) {
  uint32_t o0, o1;
  tf2x32(k0, k1, 0u, n, &o0, &o1);   // partitionable: counter = (hi=0, lo=n)
  return (o0 ^ o1) >> 9;             // 23-bit mantissa
}

// Max of fl(iw) over valid integer shifts [lo,hi] for one axis.
// iw(w) = fminf(bhi+16w, ghi) - fmaxf(blo+16w, glo) + 1 is concave in w
// (min-affine minus max-affine); fl monotone => unimodal. Max over the grid
// is at clamped floor/ceil of the continuous argmax interval endpoints.
__device__ static inline float axis_best(float blo, float bhi, float glo,
                                         float ghi, int lo, int hi) {
  #pragma clang fp contract(off)
  float t1 = (ghi - bhi) * 0.0625f;
  float t2 = (glo - blo) * 0.0625f;
  float tmin = fminf(t1, t2), tmax = fmaxf(t1, t2);
  int c1 = (int)floorf(tmin), c2 = (int)ceilf(tmax);
  int cand0 = lo, cand1 = hi;
  int cand2 = min(max(c1,     lo), hi);
  int cand3 = min(max(c1 + 1, lo), hi);
  int cand4 = min(max(c2 - 1, lo), hi);
  int cand5 = min(max(c2,     lo), hi);
  float best = -3.0e38f;
  int cands[6] = {cand0, cand1, cand2, cand3, cand4, cand5};
  #pragma unroll
  for (int i = 0; i < 6; i++) {
    float s = (float)(cands[i] << 4);
    float v = fminf(bhi + s, ghi) - fmaxf(blo + s, glo) + 1.0f;
    best = fmaxf(best, v);
  }
  return best;
}

// ---- main pass: local analytic gmax + labels/adj/mantissa/hist + select ---
__global__ __launch_bounds__(256) void k_main2(const float* __restrict__ gt,
                                               const int* __restrict__ imw_p,
                                               const int* __restrict__ imh_p,
                                               float* __restrict__ out_adj,
                                               uint32_t* __restrict__ ws,
                                               uint32_t kf0, uint32_t kf1,
                                               uint32_t kb0, uint32_t kb1) {
  #pragma clang fp contract(off)
  __shared__ float sg0[NG], sg1[NG], sg2[NG], sg3[NG], sga[NG], sgm[NG];
  __shared__ uint32_t sgmU[NG];
  __shared__ uint32_t sh[2 * NBIN];
  __shared__ unsigned long long sMask[4];
  __shared__ int sAnyZero, sLast;
  int tid = threadIdx.x;
  int b = blockIdx.x;
  int a = b >> 6, hb = (b & 63) << 2;      // anchor type, 4 rows hb..hb+3
  {
    uint4* sh4 = (uint4*)sh;
    #pragma unroll
    for (int k = 0; k < 4; k++) sh4[tid + k * 256] = make_uint4(0, 0, 0, 0);
  }
  if (tid == 0) sAnyZero = 0;
  if (tid < NG) {
    const float4 g4 = ((const float4*)gt)[tid];
    sg0[tid] = g4.x; sg1[tid] = g4.y; sg2[tid] = g4.z; sg3[tid] = g4.w;
    float gw = g4.z - g4.x + 1.0f, gh = g4.w - g4.y + 1.0f;
    sga[tid] = (gw > 0.0f && gh > 0.0f) ? gw * gh : 0.0f;
    sgmU[tid] = 0u;
  }
  __syncthreads();   // S1: gt staged, sgmU zeroed

  // local gmax: 576 (gt,type) pairs over 256 threads; LDS atomicMax on
  // float bits (IoU >= 0 -> bit order == float order).
  {
    int imwi = imw_p[0], imhi = imh_p[0];
    for (int p = tid; p < NG * NUM_A; p += 256) {
      int g = p / NUM_A, q = p - g * NUM_A;
      float b0 = BA[q][0], b1 = BA[q][1], b2 = BA[q][2], b3 = BA[q][3];
      int ib0 = (int)b0, ib1 = (int)b1, ib2 = (int)b2, ib3 = (int)b3;
      int wlo = max(0, (-ib0 + 15) >> 4);
      int whi = min(255, (imwi - ib2 - 1) >> 4);
      int hlo = max(0, (-ib1 + 15) >> 4);
      int hhi = min(255, (imhi - ib3 - 1) >> 4);
      if (wlo > whi || hlo > hhi) continue;   // no valid anchor of this type
      float iwb = axis_best(b0, b2, sg0[g], sg2[g], wlo, whi);
      float ihb = axis_best(b1, b3, sg1[g], sg3[g], hlo, hhi);
      float aw = b2 - b0 + 1.0f, ah = b3 - b1 + 1.0f;
      float aarea = aw * ah;
      float inter = (iwb > 0.0f && ihb > 0.0f) ? iwb * ihb : 0.0f;
      float den = aarea + sga[g] - inter;
      float o = inter / den;
      atomicMax(&sgmU[g], __float_as_uint(o));
    }
  }

  // per-wave y-mask: wave r handles row hb+r; lane = gt index
  {
    int wv = tid >> 6, g = tid & 63;
    float sy = (float)((hb + wv) << 4);
    float ihp = fminf(BA[a][3] + sy, sg3[g]) - fmaxf(BA[a][1] + sy, sg1[g]) + 1.0f;
    unsigned long long mk = __ballot(ihp > 0.0f);
    if (g == 0) sMask[wv] = mk;
  }
  __syncthreads();   // S2: sgmU final, sMask ready
  if (tid < NG) {
    uint32_t mm = sgmU[tid];
    sgm[tid] = __uint_as_float(mm);
    if (mm == 0u) atomicOr(&sAnyZero, 1);
  }
  __syncthreads();   // S3: sgm, sAnyZero ready

  float BA0 = BA[a][0], BA1 = BA[a][1], BA2 = BA[a][2], BA3 = BA[a][3];
  float imw = (float)imw_p[0], imh = (float)imh_p[0];
  int w = tid;
  float sx = (float)(w << 4);
  float A0 = BA0 + sx, A2 = BA2 + sx;
  float aw = A2 - A0 + 1.0f;
  float A1v[4], A3v[4];
  #pragma unroll
  for (int r = 0; r < 4; r++) {
    float sy = (float)((hb + r) << 4);
    A1v[r] = BA1 + sy; A3v[r] = BA3 + sy;
  }
  float ah = A3v[0] - A1v[0] + 1.0f;
  float aarea = aw * ah;                   // exact ints -> bit-exact
  bool xv = (A0 >= 0.0f) && (A2 < imw);

  unsigned long long mk0 = sMask[0], mk1 = sMask[1],
                     mk2 = sMask[2], mk3 = sMask[3];
  unsigned long long uni = mk0 | mk1 | mk2 | mk3;
  float amaxv[4] = {0.f, 0.f, 0.f, 0.f};
  int bgv[4] = {0, 0, 0, 0};
  uint32_t afv = 0u;
  while (uni) {
    int g = __ffsll(uni) - 1;
    uni &= uni - 1;
    float iw = fminf(A2, sg2[g]) - fmaxf(A0, sg0[g]) + 1.0f;
    if (!__any(iw > 0.0f)) continue;
    if (iw > 0.0f) {
      float base = aarea + sga[g];
      float gy1 = sg1[g], gy2 = sg3[g], gm = sgm[g];
#define DO_ROW(r, mk)                                                     \
      if ((mk >> g) & 1ull) {                                             \
        float ih = fminf(A3v[r], gy2) - fmaxf(A1v[r], gy1) + 1.0f;        \
        float inter = iw * ih;                                            \
        float o = inter / (base - inter);                                 \
        if (o > amaxv[r]) { amaxv[r] = o; bgv[r] = g; }                   \
        if (o == gm) afv |= (1u << r);                                    \
      }
      DO_ROW(0, mk0) DO_ROW(1, mk1) DO_ROW(2, mk2) DO_ROW(3, mk3)
#undef DO_ROW
    }
  }

  bool anyZ = (sAnyZero != 0);
  #pragma unroll
  for (int r = 0; r < 4; r++) {
    int hw = (hb + r) * 256 + w;
    bool valid = xv && (A1v[r] >= 0.0f) && (A3v[r] < imh);
    float amax = amaxv[r];
    bool anyfg = (((afv >> r) & 1u) || anyZ) && valid;
    uint32_t lab;
    if (!valid)                       lab = LAB_IGN;
    else if (anyfg || amax >= 0.7f)   lab = LAB_FG;
    else if (amax < 0.3f)             lab = LAB_BG;
    else                              lab = LAB_IGN;

    float adj0 = 0.f, adj1 = 0.f, adj2 = 0.f, adj3 = 0.f;
    if (valid) {
      int bg = bgv[r];
      float G0 = sg0[bg], G1 = sg1[bg], G2 = sg2[bg], G3 = sg3[bg];
      float ax = (A2 + A0) * 0.5f, ay = (A3v[r] + A1v[r]) * 0.5f;
      float gwm = G2 - G0 + 1.0f, ghm = G3 - G1 + 1.0f;
      float gx = (G2 + G0) * 0.5f, gy = (G3 + G1) * 0.5f;
      adj0 = (gx - ax) / aw;
      adj1 = (gy - ay) / ah;
      adj2 = logf(gwm / aw);
      adj3 = logf(ghm / ah);
    }
    int c4 = a * 4;
    out_adj[(c4 + 0) * HW + hw] = adj0;
    out_adj[(c4 + 1) * HW + hw] = adj1;
    out_adj[(c4 + 2) * HW + hw] = adj2;
    out_adj[(c4 + 3) * HW + hw] = adj3;

    uint32_t m = 0u;
    uint32_t n = (uint32_t)(hw * 9 + a);   // original anchor index (tie-break)
    if (lab != LAB_IGN) {
      uint32_t kk0 = (lab == LAB_FG) ? kf0 : kb0;
      uint32_t kk1 = (lab == LAB_FG) ? kf1 : kb1;
      m = mant_of(kk0, kk1, n);
      atomicAdd(&sh[((lab == LAB_FG) ? 0 : NBIN) + (m >> BIN_SHIFT)], 1u);
    }
    ws[OFF_LABM + a * HW + hw] = (lab << 24) | m;
  }

  __syncthreads();
  for (int i = tid; i < 2 * NBIN; i += 256) {
    uint32_t v = sh[i];
    if (v) atomicAdd(&ws[OFF_HF + i], v);
  }
  __syncthreads();
  if (tid == 0)
    sLast = (atomicAdd(&ws[OFF_DONE], 1u) == NBLK_MAIN - 1) ? 1 : 0;
  __syncthreads();
  if (sLast) {
    // select: histogram CDF -> subsample boundary per class
    for (int cls = 0; cls < 2; cls++) {
      uint32_t* hist = ws + (cls ? OFF_HB : OFF_HF);
      uint32_t* sel = ws + OFF_SEL + cls * 4;
      uint32_t loc[8], s = 0;
      #pragma unroll
      for (int j = 0; j < 8; j++) {
        loc[j] = __hip_atomic_load(&hist[tid * 8 + j], __ATOMIC_RELAXED,
                                   __HIP_MEMORY_SCOPE_AGENT);
        s += loc[j];
      }
      sh[tid] = s; __syncthreads();
      for (int off = 1; off < 256; off <<= 1) {
        uint32_t v = (tid >= off) ? sh[tid - off] : 0u;
        __syncthreads();
        sh[tid] += v;
        __syncthreads();
      }
      uint32_t total = sh[255];
      uint32_t K = total < CAPK ? total : CAPK;
      if (tid == 0) {
        sel[3] = K;
        if (K == 0u) { sel[0] = 0xFFFFFFFFu; sel[1] = 0u; sel[2] = 0u; }
      }
      if (K > 0u) {
        uint32_t myC = sh[tid], pvC = (tid == 0) ? 0u : sh[tid - 1];
        if (myC >= K && pvC < K) {
          uint32_t cum = pvC; int bb = tid * 8;
          for (int j = 0; j < 8; j++) {
            if (cum + loc[j] >= K) { bb = tid * 8 + j; break; }
            cum += loc[j];
          }
          sel[0] = (uint32_t)bb; sel[1] = cum; sel[2] = K - cum;
        }
      }
      __syncthreads();
    }
  }
}

// ---- emit labels + wts; boundary-bin anchors deferred entirely to the
// last block's fixup (disjoint writers -> no release fence needed) ---------
__global__ __launch_bounds__(256) void k_emitfix(float* __restrict__ out_lab,
                                                 float* __restrict__ out_wts,
                                                 uint32_t* __restrict__ ws) {
  __shared__ uint64_t sc[CAND_CAP];        // 16 KB (used by last block only)
  __shared__ int sLast;
  int tid = threadIdx.x;
  int t = blockIdx.x * 256 + tid;
  uint32_t lm = ws[OFF_LABM + t];
  uint32_t lab = lm >> 24;
  uint32_t m = lm & 0x7FFFFFu;
  uint32_t bf = ws[OFF_SEL + 0], bb = ws[OFF_SEL + 4];
  uint32_t Kf = ws[OFF_SEL + 3], Kb = ws[OFF_SEL + 7];
  float inv = 1.0f / (float)(Kf + Kb);     // 1/num_ni
  int a = t >> 16, hw = t & 65535;
  uint32_t n = (uint32_t)(hw * 9 + a);

  float outv = 2.0f, wv = 0.0f;
  bool skip = false;                        // true -> fixup is the sole writer
  if (lab == LAB_FG) {
    uint32_t bn = m >> BIN_SHIFT;
    if (bn < bf) { outv = 1.0f; wv = inv; }
    else if (bn == bf) {
      uint32_t idx = atomicAdd(&ws[OFF_CNTF], 1u);
      if (idx < CAND_CAP) {
        __hip_atomic_store((uint64_t*)(ws + OFF_CANDF) + idx,
                           ((uint64_t)m << 20) | (uint64_t)n,
                           __ATOMIC_RELAXED, __HIP_MEMORY_SCOPE_AGENT);
        skip = true;
      }
    }
  } else if (lab == LAB_BG) {
    uint32_t bn = m >> BIN_SHIFT;
    if (bn < bb) { outv = 0.0f; }
    else if (bn == bb) {
      uint32_t idx = atomicAdd(&ws[OFF_CNTB], 1u);
      if (idx < CAND_CAP) {
        __hip_atomic_store((uint64_t*)(ws + OFF_CANDB) + idx,
                           ((uint64_t)m << 20) | (uint64_t)n,
                           __ATOMIC_RELAXED, __HIP_MEMORY_SCOPE_AGENT);
        skip = true;
      }
    }
  }
  if (!skip) {
    out_lab[t] = outv;
    int c4 = a * 4;
    out_wts[(c4 + 0) * HW + hw] = wv;
    out_wts[(c4 + 1) * HW + hw] = wv;
    out_wts[(c4 + 2) * HW + hw] = wv;
    out_wts[(c4 + 3) * HW + hw] = wv;
  }

  // Publish: drain this wave's VMEM (candidate atomic stores are then AT the
  // IF coherence point). Wave-local wait — NO cache writeback/invalidate.
  asm volatile("s_waitcnt vmcnt(0)" ::: "memory");
  __syncthreads();
  if (tid == 0)
    sLast = (__hip_atomic_fetch_add(&ws[OFF_DONE2], 1u, __ATOMIC_RELAXED,
                                    __HIP_MEMORY_SCOPE_AGENT)
             == NBLK_EMIT - 1) ? 1 : 0;
  __syncthreads();
  if (sLast) {
    for (int cls = 0; cls < 2; cls++) {
      uint32_t cnt = __hip_atomic_load(&ws[cls == 0 ? OFF_CNTF : OFF_CNTB],
                                       __ATOMIC_RELAXED,
                                       __HIP_MEMORY_SCOPE_AGENT);
      uint32_t C = cnt < CAND_CAP ? cnt : CAND_CAP;
      uint32_t need = __hip_atomic_load(&ws[OFF_SEL + cls * 4 + 2],
                                        __ATOMIC_RELAXED,
                                        __HIP_MEMORY_SCOPE_AGENT);
      const uint64_t* cand =
          (const uint64_t*)(ws + (cls == 0 ? OFF_CANDF : OFF_CANDB));
      for (uint32_t i = tid; i < C; i += 256)
        sc[i] = __hip_atomic_load(&cand[i], __ATOMIC_RELAXED,
                                  __HIP_MEMORY_SCOPE_AGENT);
      __syncthreads();
      for (uint32_t i = tid; i < C; i += 256) {
        uint64_t k = sc[i];
        uint32_t rr = 0;
        for (uint32_t j = 0; j < C; j++) rr += (sc[j] < k) ? 1u : 0u;
        bool kept = (rr < need);           // keys unique -> exactly need kept
        uint32_t nn = (uint32_t)(k & 0xFFFFFu);
        uint32_t aa = nn % 9u, hww = nn / 9u;
        uint32_t tt = aa * HW + hww;
        float lv = kept ? (cls == 0 ? 1.0f : 0.0f) : 2.0f;
        float wvv = (kept && cls == 0) ? inv : 0.0f;
        // atomic stores -> performed at IF; immune to other XCDs' L2 state
        __hip_atomic_store(&out_lab[tt], lv, __ATOMIC_RELAXED,
                           __HIP_MEMORY_SCOPE_AGENT);
        #pragma unroll
        for (int j2 = 0; j2 < 4; j2++)
          __hip_atomic_store(&out_wts[(aa * 4 + j2) * HW + hww], wvv,
                             __ATOMIC_RELAXED, __HIP_MEMORY_SCOPE_AGENT);
      }
      __syncthreads();
    }
  }
}

extern "C" void kernel_launch(void* const* d_in, const int* in_sizes, int n_in,
                              void* d_out, int out_size, void* d_ws,
                              size_t ws_size, hipStream_t stream) {
  const float* gt  = (const float*)d_in[1];
  const int*   imw = (const int*)d_in[2];
  const int*   imh = (const int*)d_in[3];
  float* out      = (float*)d_out;
  float* out_lab  = out;                   // 589824
  float* out_adj  = out + N_ANCH;          // 4*589824
  float* out_wts  = out + 5 * N_ANCH;      // 4*589824
  uint32_t* ws = (uint32_t*)d_ws;          // ~2.41 MB used

  uint32_t kf0, kf1, kb0, kb1;
  tf2x32(0u, 42u, 0u, 0u, &kf0, &kf1);
  tf2x32(0u, 42u, 0u, 1u, &kb0, &kb1);

  hipMemsetAsync(ws, 0, CTRL_WORDS * sizeof(uint32_t), stream);
  hipLaunchKernelGGL(k_main2, dim3(NBLK_MAIN), dim3(256), 0, stream, gt, imw,
                     imh, out_adj, ws, kf0, kf1, kb0, kb1);
  hipLaunchKernelGGL(k_emitfix, dim3(NBLK_EMIT), dim3(256), 0, stream,
                     out_lab, out_wts, ws);
}

// Round 5
// 113.345 us; speedup vs baseline: 2.7202x; 1.2977x over previous
//
#include <hip/hip_runtime.h>
#include <stdint.h>

// ===========================================================================
// AnchorDataGenerator (Faster R-CNN anchor target layer), MI355X / gfx950
// Round 8: tree done-counters. Measured: same-address agent-scope atomic RMW
// serializes at ~28ns (2304-block flat counter = 64us of idle). Replace flat
// arrival counters with 2-level trees on 64B-strided addresses:
//   k_main2:  576 -> 32 subs (18 each) -> root(32). serial ~50 RMW ~1.4us
//   k_emitfix:2304 -> 64 subs (36 each) -> root(64). serial ~100 RMW ~2.8us
// Everything else verbatim from Round 7 (passed, absmax 0):
//   memset(22.6KB ctrl) -> k_main2 (analytic gmax + IoU + hist + select)
//   -> k_emitfix (emit + disjoint-writer boundary candidates + fixup in the
//   completing block). Publish discipline: __syncthreads drains vmcnt before
//   each arrival RMW; relaxed agent atomics only; NO cache-maintenance
//   fences (74us lesson), NO flat arrival counters (64us lesson).
// ===========================================================================

#define NUM_A 9
#define HW 65536
#define N_ANCH 589824
#define NG 64
#define CAPK 128u
#define NBIN 2048
#define BIN_SHIFT 12
#define CAND_CAP 2048

#define LAB_BG 0u
#define LAB_FG 1u
#define LAB_IGN 2u

// workspace layout (u32 units)
#define OFF_HF    0
#define OFF_HB    NBIN                       // 2048
#define OFF_CNTF  (2*NBIN)                   // 4096
#define OFF_CNTB  (OFF_CNTF + 1)             // 4097
#define OFF_ROOT1 (OFF_CNTF + 2)             // 4098 (k_main2 root counter)
#define OFF_ROOT2 (OFF_CNTF + 3)             // 4099 (k_emitfix root counter)
#define OFF_SEL   (OFF_CNTF + 4)             // 4100..4107 {bin,below,need,K}x2
#define OFF_SUB1  4112                       // 32 sub-counters, stride 16 u32
#define OFF_SUB2  (OFF_SUB1 + 32*16)         // 4624: 64 sub-counters, stride 16
#define CTRL_WORDS (OFF_SUB2 + 64*16)        // 5648 words = 22.6 KB memset
#define OFF_CANDF CTRL_WORDS                 // 5648, 8B aligned (even)
#define OFF_CANDB (OFF_CANDF + 2*CAND_CAP)   // 9744
#define OFF_LABM  (OFF_CANDB + 2*CAND_CAP)   // 13840 (+589824 -> 2.41 MB)

#define NBLK_MAIN 576
#define NBLK_EMIT (N_ANCH / 256)             // 2304
#define SUB1_N 32
#define SUB1_Q (NBLK_MAIN / SUB1_N)          // 18
#define SUB2_N 64
#define SUB2_Q (NBLK_EMIT / SUB2_N)          // 36

__constant__ float BA[NUM_A][4] = {
  { -84.f,  -40.f,  99.f,  55.f}, {-176.f,  -88.f, 191.f, 103.f},
  {-360.f, -184.f, 375.f, 199.f}, { -56.f,  -56.f,  71.f,  71.f},
  {-120.f, -120.f, 135.f, 135.f}, {-248.f, -248.f, 263.f, 263.f},
  { -36.f,  -80.f,  51.f,  95.f}, { -80.f, -168.f,  95.f, 183.f},
  {-168.f, -344.f, 183.f, 359.f}};

__host__ __device__ static inline void tf2x32(uint32_t k0, uint32_t k1,
                                              uint32_t x0, uint32_t x1,
                                              uint32_t* o0, uint32_t* o1) {
  const uint32_t ks2 = k0 ^ k1 ^ 0x1BD11BDAu;
#define TF_R(r) { x0 += x1; x1 = (x1 << (r)) | (x1 >> (32 - (r))); x1 ^= x0; }
  x0 += k0; x1 += k1;
  TF_R(13) TF_R(15) TF_R(26) TF_R(6)
  x0 += k1;  x1 += ks2 + 1u;
  TF_R(17) TF_R(29) TF_R(16) TF_R(24)
  x0 += ks2; x1 += k0 + 2u;
  TF_R(13) TF_R(15) TF_R(26) TF_R(6)
  x0 += k0;  x1 += k1 + 3u;
  TF_R(17) TF_R(29) TF_R(16) TF_R(24)
  x0 += k1;  x1 += ks2 + 4u;
  TF_R(13) TF_R(15) TF_R(26) TF_R(6)
  x0 += ks2; x1 += k0 + 5u;
#undef TF_R
  *o0 = x0; *o1 = x1;
}

__device__ static inline uint32_t mant_of(uint32_t k0, uint32_t k1, uint32_t n) {
  uint32_t o0, o1;
  tf2x32(k0, k1, 0u, n, &o0, &o1);   // partitionable: counter = (hi=0, lo=n)
  return (o0 ^ o1) >> 9;             // 23-bit mantissa
}

// Max of fl(iw) over valid integer shifts [lo,hi] for one axis.
// iw(w) = fminf(bhi+16w, ghi) - fmaxf(blo+16w, glo) + 1 is concave in w
// (min-affine minus max-affine); fl monotone => unimodal. Max over the grid
// is at clamped floor/ceil of the continuous argmax interval endpoints.
__device__ static inline float axis_best(float blo, float bhi, float glo,
                                         float ghi, int lo, int hi) {
  #pragma clang fp contract(off)
  float t1 = (ghi - bhi) * 0.0625f;
  float t2 = (glo - blo) * 0.0625f;
  float tmin = fminf(t1, t2), tmax = fmaxf(t1, t2);
  int c1 = (int)floorf(tmin), c2 = (int)ceilf(tmax);
  int cand0 = lo, cand1 = hi;
  int cand2 = min(max(c1,     lo), hi);
  int cand3 = min(max(c1 + 1, lo), hi);
  int cand4 = min(max(c2 - 1, lo), hi);
  int cand5 = min(max(c2,     lo), hi);
  float best = -3.0e38f;
  int cands[6] = {cand0, cand1, cand2, cand3, cand4, cand5};
  #pragma unroll
  for (int i = 0; i < 6; i++) {
    float s = (float)(cands[i] << 4);
    float v = fminf(bhi + s, ghi) - fmaxf(blo + s, glo) + 1.0f;
    best = fmaxf(best, v);
  }
  return best;
}

// ---- main pass: local analytic gmax + labels/adj/mantissa/hist + select ---
__global__ __launch_bounds__(256) void k_main2(const float* __restrict__ gt,
                                               const int* __restrict__ imw_p,
                                               const int* __restrict__ imh_p,
                                               float* __restrict__ out_adj,
                                               uint32_t* __restrict__ ws,
                                               uint32_t kf0, uint32_t kf1,
                                               uint32_t kb0, uint32_t kb1) {
  #pragma clang fp contract(off)
  __shared__ float sg0[NG], sg1[NG], sg2[NG], sg3[NG], sga[NG], sgm[NG];
  __shared__ uint32_t sgmU[NG];
  __shared__ uint32_t sh[2 * NBIN];
  __shared__ unsigned long long sMask[4];
  __shared__ int sAnyZero, sLast;
  int tid = threadIdx.x;
  int b = blockIdx.x;
  int a = b >> 6, hb = (b & 63) << 2;      // anchor type, 4 rows hb..hb+3
  {
    uint4* sh4 = (uint4*)sh;
    #pragma unroll
    for (int k = 0; k < 4; k++) sh4[tid + k * 256] = make_uint4(0, 0, 0, 0);
  }
  if (tid == 0) sAnyZero = 0;
  if (tid < NG) {
    const float4 g4 = ((const float4*)gt)[tid];
    sg0[tid] = g4.x; sg1[tid] = g4.y; sg2[tid] = g4.z; sg3[tid] = g4.w;
    float gw = g4.z - g4.x + 1.0f, gh = g4.w - g4.y + 1.0f;
    sga[tid] = (gw > 0.0f && gh > 0.0f) ? gw * gh : 0.0f;
    sgmU[tid] = 0u;
  }
  __syncthreads();   // S1: gt staged, sgmU zeroed

  // local gmax: 576 (gt,type) pairs over 256 threads; LDS atomicMax on
  // float bits (IoU >= 0 -> bit order == float order).
  {
    int imwi = imw_p[0], imhi = imh_p[0];
    for (int p = tid; p < NG * NUM_A; p += 256) {
      int g = p / NUM_A, q = p - g * NUM_A;
      float b0 = BA[q][0], b1 = BA[q][1], b2 = BA[q][2], b3 = BA[q][3];
      int ib0 = (int)b0, ib1 = (int)b1, ib2 = (int)b2, ib3 = (int)b3;
      int wlo = max(0, (-ib0 + 15) >> 4);
      int whi = min(255, (imwi - ib2 - 1) >> 4);
      int hlo = max(0, (-ib1 + 15) >> 4);
      int hhi = min(255, (imhi - ib3 - 1) >> 4);
      if (wlo > whi || hlo > hhi) continue;   // no valid anchor of this type
      float iwb = axis_best(b0, b2, sg0[g], sg2[g], wlo, whi);
      float ihb = axis_best(b1, b3, sg1[g], sg3[g], hlo, hhi);
      float aw = b2 - b0 + 1.0f, ah = b3 - b1 + 1.0f;
      float aarea = aw * ah;
      float inter = (iwb > 0.0f && ihb > 0.0f) ? iwb * ihb : 0.0f;
      float den = aarea + sga[g] - inter;
      float o = inter / den;
      atomicMax(&sgmU[g], __float_as_uint(o));
    }
  }

  // per-wave y-mask: wave r handles row hb+r; lane = gt index
  {
    int wv = tid >> 6, g = tid & 63;
    float sy = (float)((hb + wv) << 4);
    float ihp = fminf(BA[a][3] + sy, sg3[g]) - fmaxf(BA[a][1] + sy, sg1[g]) + 1.0f;
    unsigned long long mk = __ballot(ihp > 0.0f);
    if (g == 0) sMask[wv] = mk;
  }
  __syncthreads();   // S2: sgmU final, sMask ready
  if (tid < NG) {
    uint32_t mm = sgmU[tid];
    sgm[tid] = __uint_as_float(mm);
    if (mm == 0u) atomicOr(&sAnyZero, 1);
  }
  __syncthreads();   // S3: sgm, sAnyZero ready

  float BA0 = BA[a][0], BA1 = BA[a][1], BA2 = BA[a][2], BA3 = BA[a][3];
  float imw = (float)imw_p[0], imh = (float)imh_p[0];
  int w = tid;
  float sx = (float)(w << 4);
  float A0 = BA0 + sx, A2 = BA2 + sx;
  float aw = A2 - A0 + 1.0f;
  float A1v[4], A3v[4];
  #pragma unroll
  for (int r = 0; r < 4; r++) {
    float sy = (float)((hb + r) << 4);
    A1v[r] = BA1 + sy; A3v[r] = BA3 + sy;
  }
  float ah = A3v[0] - A1v[0] + 1.0f;
  float aarea = aw * ah;                   // exact ints -> bit-exact
  bool xv = (A0 >= 0.0f) && (A2 < imw);

  unsigned long long mk0 = sMask[0], mk1 = sMask[1],
                     mk2 = sMask[2], mk3 = sMask[3];
  unsigned long long uni = mk0 | mk1 | mk2 | mk3;
  float amaxv[4] = {0.f, 0.f, 0.f, 0.f};
  int bgv[4] = {0, 0, 0, 0};
  uint32_t afv = 0u;
  while (uni) {
    int g = __ffsll(uni) - 1;
    uni &= uni - 1;
    float iw = fminf(A2, sg2[g]) - fmaxf(A0, sg0[g]) + 1.0f;
    if (!__any(iw > 0.0f)) continue;
    if (iw > 0.0f) {
      float base = aarea + sga[g];
      float gy1 = sg1[g], gy2 = sg3[g], gm = sgm[g];
#define DO_ROW(r, mk)                                                     \
      if ((mk >> g) & 1ull) {                                             \
        float ih = fminf(A3v[r], gy2) - fmaxf(A1v[r], gy1) + 1.0f;        \
        float inter = iw * ih;                                            \
        float o = inter / (base - inter);                                 \
        if (o > amaxv[r]) { amaxv[r] = o; bgv[r] = g; }                   \
        if (o == gm) afv |= (1u << r);                                    \
      }
      DO_ROW(0, mk0) DO_ROW(1, mk1) DO_ROW(2, mk2) DO_ROW(3, mk3)
#undef DO_ROW
    }
  }

  bool anyZ = (sAnyZero != 0);
  #pragma unroll
  for (int r = 0; r < 4; r++) {
    int hw = (hb + r) * 256 + w;
    bool valid = xv && (A1v[r] >= 0.0f) && (A3v[r] < imh);
    float amax = amaxv[r];
    bool anyfg = (((afv >> r) & 1u) || anyZ) && valid;
    uint32_t lab;
    if (!valid)                       lab = LAB_IGN;
    else if (anyfg || amax >= 0.7f)   lab = LAB_FG;
    else if (amax < 0.3f)             lab = LAB_BG;
    else                              lab = LAB_IGN;

    float adj0 = 0.f, adj1 = 0.f, adj2 = 0.f, adj3 = 0.f;
    if (valid) {
      int bg = bgv[r];
      float G0 = sg0[bg], G1 = sg1[bg], G2 = sg2[bg], G3 = sg3[bg];
      float ax = (A2 + A0) * 0.5f, ay = (A3v[r] + A1v[r]) * 0.5f;
      float gwm = G2 - G0 + 1.0f, ghm = G3 - G1 + 1.0f;
      float gx = (G2 + G0) * 0.5f, gy = (G3 + G1) * 0.5f;
      adj0 = (gx - ax) / aw;
      adj1 = (gy - ay) / ah;
      adj2 = logf(gwm / aw);
      adj3 = logf(ghm / ah);
    }
    int c4 = a * 4;
    out_adj[(c4 + 0) * HW + hw] = adj0;
    out_adj[(c4 + 1) * HW + hw] = adj1;
    out_adj[(c4 + 2) * HW + hw] = adj2;
    out_adj[(c4 + 3) * HW + hw] = adj3;

    uint32_t m = 0u;
    uint32_t n = (uint32_t)(hw * 9 + a);   // original anchor index (tie-break)
    if (lab != LAB_IGN) {
      uint32_t kk0 = (lab == LAB_FG) ? kf0 : kb0;
      uint32_t kk1 = (lab == LAB_FG) ? kf1 : kb1;
      m = mant_of(kk0, kk1, n);
      atomicAdd(&sh[((lab == LAB_FG) ? 0 : NBIN) + (m >> BIN_SHIFT)], 1u);
    }
    ws[OFF_LABM + a * HW + hw] = (lab << 24) | m;
  }

  __syncthreads();
  for (int i = tid; i < 2 * NBIN; i += 256) {
    uint32_t v = sh[i];
    if (v) atomicAdd(&ws[OFF_HF + i], v);
  }
  // barrier lowers with s_waitcnt vmcnt(0): all this block's hist atomics
  // and LABM stores are performed before the arrival RMW below.
  __syncthreads();
  if (tid == 0) {
    int lastF = 0;
    uint32_t v = atomicAdd(&ws[OFF_SUB1 + (b & (SUB1_N - 1)) * 16], 1u);
    if (v == SUB1_Q - 1) {                 // sub-group complete -> root
      uint32_t r = atomicAdd(&ws[OFF_ROOT1], 1u);
      if (r == SUB1_N - 1) lastF = 1;      // all sub-groups complete
    }
    sLast = lastF;
  }
  __syncthreads();
  if (sLast) {
    // select: histogram CDF -> subsample boundary per class
    for (int cls = 0; cls < 2; cls++) {
      uint32_t* hist = ws + (cls ? OFF_HB : OFF_HF);
      uint32_t* sel = ws + OFF_SEL + cls * 4;
      uint32_t loc[8], s = 0;
      #pragma unroll
      for (int j = 0; j < 8; j++) {
        loc[j] = __hip_atomic_load(&hist[tid * 8 + j], __ATOMIC_RELAXED,
                                   __HIP_MEMORY_SCOPE_AGENT);
        s += loc[j];
      }
      sh[tid] = s; __syncthreads();
      for (int off = 1; off < 256; off <<= 1) {
        uint32_t v = (tid >= off) ? sh[tid - off] : 0u;
        __syncthreads();
        sh[tid] += v;
        __syncthreads();
      }
      uint32_t total = sh[255];
      uint32_t K = total < CAPK ? total : CAPK;
      if (tid == 0) {
        sel[3] = K;
        if (K == 0u) { sel[0] = 0xFFFFFFFFu; sel[1] = 0u; sel[2] = 0u; }
      }
      if (K > 0u) {
        uint32_t myC = sh[tid], pvC = (tid == 0) ? 0u : sh[tid - 1];
        if (myC >= K && pvC < K) {
          uint32_t cum = pvC; int bb = tid * 8;
          for (int j = 0; j < 8; j++) {
            if (cum + loc[j] >= K) { bb = tid * 8 + j; break; }
            cum += loc[j];
          }
          sel[0] = (uint32_t)bb; sel[1] = cum; sel[2] = K - cum;
        }
      }
      __syncthreads();
    }
  }
}

// ---- emit labels + wts; boundary-bin anchors deferred entirely to the
// completing block's fixup (disjoint writers -> no release fence needed) ----
__global__ __launch_bounds__(256) void k_emitfix(float* __restrict__ out_lab,
                                                 float* __restrict__ out_wts,
                                                 uint32_t* __restrict__ ws) {
  __shared__ uint64_t sc[CAND_CAP];        // 16 KB (used by last block only)
  __shared__ int sLast;
  int tid = threadIdx.x;
  int t = blockIdx.x * 256 + tid;
  uint32_t lm = ws[OFF_LABM + t];
  uint32_t lab = lm >> 24;
  uint32_t m = lm & 0x7FFFFFu;
  uint32_t bf = ws[OFF_SEL + 0], bb = ws[OFF_SEL + 4];
  uint32_t Kf = ws[OFF_SEL + 3], Kb = ws[OFF_SEL + 7];
  float inv = 1.0f / (float)(Kf + Kb);     // 1/num_ni
  int a = t >> 16, hw = t & 65535;
  uint32_t n = (uint32_t)(hw * 9 + a);

  float outv = 2.0f, wv = 0.0f;
  bool skip = false;                        // true -> fixup is the sole writer
  if (lab == LAB_FG) {
    uint32_t bn = m >> BIN_SHIFT;
    if (bn < bf) { outv = 1.0f; wv = inv; }
    else if (bn == bf) {
      uint32_t idx = atomicAdd(&ws[OFF_CNTF], 1u);
      if (idx < CAND_CAP) {
        __hip_atomic_store((uint64_t*)(ws + OFF_CANDF) + idx,
                           ((uint64_t)m << 20) | (uint64_t)n,
                           __ATOMIC_RELAXED, __HIP_MEMORY_SCOPE_AGENT);
        skip = true;
      }
    }
  } else if (lab == LAB_BG) {
    uint32_t bn = m >> BIN_SHIFT;
    if (bn < bb) { outv = 0.0f; }
    else if (bn == bb) {
      uint32_t idx = atomicAdd(&ws[OFF_CNTB], 1u);
      if (idx < CAND_CAP) {
        __hip_atomic_store((uint64_t*)(ws + OFF_CANDB) + idx,
                           ((uint64_t)m << 20) | (uint64_t)n,
                           __ATOMIC_RELAXED, __HIP_MEMORY_SCOPE_AGENT);
        skip = true;
      }
    }
  }
  if (!skip) {
    out_lab[t] = outv;
    int c4 = a * 4;
    out_wts[(c4 + 0) * HW + hw] = wv;
    out_wts[(c4 + 1) * HW + hw] = wv;
    out_wts[(c4 + 2) * HW + hw] = wv;
    out_wts[(c4 + 3) * HW + hw] = wv;
  }

  // Publish: barrier drains this block's VMEM (candidate atomic stores are
  // then performed at the IF coherence point). No cache maintenance.
  asm volatile("s_waitcnt vmcnt(0)" ::: "memory");
  __syncthreads();
  if (tid == 0) {
    int lastF = 0;
    uint32_t v = atomicAdd(&ws[OFF_SUB2 + (blockIdx.x & (SUB2_N - 1)) * 16], 1u);
    if (v == SUB2_Q - 1) {                 // sub-group complete -> root
      uint32_t r = atomicAdd(&ws[OFF_ROOT2], 1u);
      if (r == SUB2_N - 1) lastF = 1;      // all blocks complete
    }
    sLast = lastF;
  }
  __syncthreads();
  if (sLast) {
    for (int cls = 0; cls < 2; cls++) {
      uint32_t cnt = __hip_atomic_load(&ws[cls == 0 ? OFF_CNTF : OFF_CNTB],
                                       __ATOMIC_RELAXED,
                                       __HIP_MEMORY_SCOPE_AGENT);
      uint32_t C = cnt < CAND_CAP ? cnt : CAND_CAP;
      uint32_t need = __hip_atomic_load(&ws[OFF_SEL + cls * 4 + 2],
                                        __ATOMIC_RELAXED,
                                        __HIP_MEMORY_SCOPE_AGENT);
      const uint64_t* cand =
          (const uint64_t*)(ws + (cls == 0 ? OFF_CANDF : OFF_CANDB));
      for (uint32_t i = tid; i < C; i += 256)
        sc[i] = __hip_atomic_load(&cand[i], __ATOMIC_RELAXED,
                                  __HIP_MEMORY_SCOPE_AGENT);
      __syncthreads();
      for (uint32_t i = tid; i < C; i += 256) {
        uint64_t k = sc[i];
        uint32_t rr = 0;
        for (uint32_t j = 0; j < C; j++) rr += (sc[j] < k) ? 1u : 0u;
        bool kept = (rr < need);           // keys unique -> exactly need kept
        uint32_t nn = (uint32_t)(k & 0xFFFFFu);
        uint32_t aa = nn % 9u, hww = nn / 9u;
        uint32_t tt = aa * HW + hww;
        float lv = kept ? (cls == 0 ? 1.0f : 0.0f) : 2.0f;
        float wvv = (kept && cls == 0) ? inv : 0.0f;
        // atomic stores -> performed at IF; immune to other XCDs' L2 state
        __hip_atomic_store(&out_lab[tt], lv, __ATOMIC_RELAXED,
                           __HIP_MEMORY_SCOPE_AGENT);
        #pragma unroll
        for (int j2 = 0; j2 < 4; j2++)
          __hip_atomic_store(&out_wts[(aa * 4 + j2) * HW + hww], wvv,
                             __ATOMIC_RELAXED, __HIP_MEMORY_SCOPE_AGENT);
      }
      __syncthreads();
    }
  }
}

extern "C" void kernel_launch(void* const* d_in, const int* in_sizes, int n_in,
                              void* d_out, int out_size, void* d_ws,
                              size_t ws_size, hipStream_t stream) {
  const float* gt  = (const float*)d_in[1];
  const int*   imw = (const int*)d_in[2];
  const int*   imh = (const int*)d_in[3];
  float* out      = (float*)d_out;
  float* out_lab  = out;                   // 589824
  float* out_adj  = out + N_ANCH;          // 4*589824
  float* out_wts  = out + 5 * N_ANCH;      // 4*589824
  uint32_t* ws = (uint32_t*)d_ws;          // ~2.42 MB used

  uint32_t kf0, kf1, kb0, kb1;
  tf2x32(0u, 42u, 0u, 0u, &kf0, &kf1);
  tf2x32(0u, 42u, 0u, 1u, &kb0, &kb1);

  hipMemsetAsync(ws, 0, CTRL_WORDS * sizeof(uint32_t), stream);
  hipLaunchKernelGGL(k_main2, dim3(NBLK_MAIN), dim3(256), 0, stream, gt, imw,
                     imh, out_adj, ws, kf0, kf1, kb0, kb1);
  hipLaunchKernelGGL(k_emitfix, dim3(NBLK_EMIT), dim3(256), 0, stream,
                     out_lab, out_wts, ws);
}